// Round 4
// baseline (1744.126 us; speedup 1.0000x reference)
//
#include <hip/hip_runtime.h>

#define NVAR 1000000
#define NCON 500000
#define HFE 10
#define NXCD 8

__device__ __forceinline__ unsigned get_xcd() {
    unsigned x;
    asm volatile("s_getreg_b32 %0, hwreg(HW_REG_XCC_ID)" : "=s"(x));
    return x & (NXCD - 1);
}

// ---- degree count + per-edge local rank, per-XCD histogram copies ----
// Atomicity needed only within one XCD (each copy touched by one XCD only),
// so workgroup-scope atomics suffice and can execute in the XCD-local L2.
__global__ __launch_bounds__(256) void k_degree_rank(const int4* __restrict__ src4,
                                                     const int4* __restrict__ dst4,
                                                     ushort4* __restrict__ rkS,
                                                     ushort4* __restrict__ rkD,
                                                     unsigned int* __restrict__ dvc,  // [NXCD][NVAR]
                                                     unsigned int* __restrict__ dcc,  // [NXCD][NCON]
                                                     int ne4) {
    int t = blockIdx.x * blockDim.x + threadIdx.x;
    if (t >= ne4) return;
    unsigned xcd = get_xcd();
    unsigned int* dv = dvc + (size_t)xcd * NVAR;
    unsigned int* dc = dcc + (size_t)xcd * NCON;
    int4 s = src4[t];
    int4 d = dst4[t];
    unsigned r0 = __hip_atomic_fetch_add(&dv[s.x], 1u, __ATOMIC_RELAXED, __HIP_MEMORY_SCOPE_WORKGROUP);
    unsigned r1 = __hip_atomic_fetch_add(&dv[s.y], 1u, __ATOMIC_RELAXED, __HIP_MEMORY_SCOPE_WORKGROUP);
    unsigned r2 = __hip_atomic_fetch_add(&dv[s.z], 1u, __ATOMIC_RELAXED, __HIP_MEMORY_SCOPE_WORKGROUP);
    unsigned r3 = __hip_atomic_fetch_add(&dv[s.w], 1u, __ATOMIC_RELAXED, __HIP_MEMORY_SCOPE_WORKGROUP);
    unsigned q0 = __hip_atomic_fetch_add(&dc[d.x], 1u, __ATOMIC_RELAXED, __HIP_MEMORY_SCOPE_WORKGROUP);
    unsigned q1 = __hip_atomic_fetch_add(&dc[d.y], 1u, __ATOMIC_RELAXED, __HIP_MEMORY_SCOPE_WORKGROUP);
    unsigned q2 = __hip_atomic_fetch_add(&dc[d.z], 1u, __ATOMIC_RELAXED, __HIP_MEMORY_SCOPE_WORKGROUP);
    unsigned q3 = __hip_atomic_fetch_add(&dc[d.w], 1u, __ATOMIC_RELAXED, __HIP_MEMORY_SCOPE_WORKGROUP);
    unsigned hx = xcd << 8;
    rkS[t] = make_ushort4((unsigned short)(hx | r0), (unsigned short)(hx | r1),
                          (unsigned short)(hx | r2), (unsigned short)(hx | r3));
    rkD[t] = make_ushort4((unsigned short)(hx | q0), (unsigned short)(hx | q1),
                          (unsigned short)(hx | q2), (unsigned short)(hx | q3));
}

// ---- reduce 8 per-XCD copies -> total degree + per-node per-XCD u8 offsets ----
__global__ __launch_bounds__(256) void k_xcdoff(const unsigned int* __restrict__ copies, // [NXCD][n]
                                                unsigned int* __restrict__ deg,
                                                unsigned char* __restrict__ off,        // [n][NXCD]
                                                int n) {
    int i = blockIdx.x * blockDim.x + threadIdx.x;
    if (i >= n) return;
    unsigned p = 0;
    unsigned long long pk = 0;
#pragma unroll
    for (int x = 0; x < NXCD; x++) {
        unsigned cx = copies[(size_t)x * n + i];
        pk |= (unsigned long long)(p & 255u) << (8 * x);
        p += cx;
    }
    deg[i] = p;
    *(unsigned long long*)(off + (size_t)i * NXCD) = pk;
}

// ---------------- exclusive scan, 1024 elements / block ----------------
__global__ __launch_bounds__(256) void k_scan_blocks(const unsigned int* __restrict__ in,
                                                     unsigned int* __restrict__ out,
                                                     unsigned int* __restrict__ bsum,
                                                     int n) {
    __shared__ unsigned int sT[256];
    int base = blockIdx.x * 1024 + threadIdx.x * 4;
    unsigned int v0 = 0, v1 = 0, v2 = 0, v3 = 0;
    if (base + 3 < n) {
        uint4 u = *(const uint4*)(in + base);
        v0 = u.x; v1 = u.y; v2 = u.z; v3 = u.w;
    } else {
        if (base     < n) v0 = in[base];
        if (base + 1 < n) v1 = in[base + 1];
        if (base + 2 < n) v2 = in[base + 2];
        if (base + 3 < n) v3 = in[base + 3];
    }
    sT[threadIdx.x] = v0 + v1 + v2 + v3;
    __syncthreads();
    for (int d = 1; d < 256; d <<= 1) {
        unsigned int add = (threadIdx.x >= (unsigned)d) ? sT[threadIdx.x - d] : 0u;
        __syncthreads();
        sT[threadIdx.x] += add;
        __syncthreads();
    }
    unsigned int excl = (threadIdx.x == 0) ? 0u : sT[threadIdx.x - 1];
    if (base     < n) out[base]     = excl;
    if (base + 1 < n) out[base + 1] = excl + v0;
    if (base + 2 < n) out[base + 2] = excl + v0 + v1;
    if (base + 3 < n) out[base + 3] = excl + v0 + v1 + v2;
    if (threadIdx.x == 255 && bsum) bsum[blockIdx.x] = sT[255];
}

__global__ __launch_bounds__(256) void k_scan_add(unsigned int* __restrict__ data,
                                                  const unsigned int* __restrict__ bscan,
                                                  int n) {
    int base = blockIdx.x * 1024 + threadIdx.x * 4;
    unsigned int add = bscan[blockIdx.x];
    if (base + 3 < n) {
        uint4 u = *(const uint4*)(data + base);
        u.x += add; u.y += add; u.z += add; u.w += add;
        *(uint4*)(data + base) = u;
    } else {
        if (base     < n) data[base]     += add;
        if (base + 1 < n) data[base + 1] += add;
        if (base + 2 < n) data[base + 2] += add;
        if (base + 3 < n) data[base + 3] += add;
    }
}

// ---------------- var embedding, prescaled by rsqrt(deg) ----------------
__global__ __launch_bounds__(256) void k_xvar(const float* __restrict__ var_c,
                                              const float* __restrict__ var_x,
                                              const unsigned int* __restrict__ deg_var,
                                              const float* __restrict__ Wv,
                                              const float* __restrict__ bv,
                                              float* __restrict__ Xs, int n) {
    int i = blockIdx.x * blockDim.x + threadIdx.x;
    if (i >= n) return;
    float c = var_c[i], x = var_x[i];
    float rs = rsqrtf(fmaxf((float)deg_var[i], 1.0f));
    float o[HFE];
#pragma unroll
    for (int j = 0; j < HFE; j++) {
        float t = fmaf(c, Wv[j], fmaf(x, Wv[HFE + j], bv[j]));
        o[j] = fmaxf(t, 0.0f) * rs;
    }
    float2* dst2 = (float2*)(Xs + (size_t)i * HFE);
#pragma unroll
    for (int j = 0; j < 5; j++) dst2[j] = make_float2(o[2 * j], o[2 * j + 1]);
}

// ---- CSR fill, atomic-free: csr[cur[key] + off[key][xcd] + lrank] = {val, w} ----
__global__ __launch_bounds__(256) void k_fill(const int4* __restrict__ key4,
                                              const int4* __restrict__ val4,
                                              const float4* __restrict__ w4,
                                              const ushort4* __restrict__ rk4,
                                              const unsigned int* __restrict__ cur,
                                              const unsigned char* __restrict__ off, // [n][NXCD]
                                              int2* __restrict__ csr, int ne4) {
    int t = blockIdx.x * blockDim.x + threadIdx.x;
    if (t >= ne4) return;
    int4 k = key4[t];
    int4 v = val4[t];
    float4 w = w4[t];
    ushort4 r = rk4[t];
    unsigned int p0 = cur[k.x] + off[(size_t)k.x * NXCD + (r.x >> 8)] + (r.x & 255u);
    unsigned int p1 = cur[k.y] + off[(size_t)k.y * NXCD + (r.y >> 8)] + (r.y & 255u);
    unsigned int p2 = cur[k.z] + off[(size_t)k.z * NXCD + (r.z >> 8)] + (r.z & 255u);
    unsigned int p3 = cur[k.w] + off[(size_t)k.w * NXCD + (r.w >> 8)] + (r.w & 255u);
    csr[p0] = make_int2(v.x, __float_as_int(w.x));
    csr[p1] = make_int2(v.y, __float_as_int(w.y));
    csr[p2] = make_int2(v.z, __float_as_int(w.z));
    csr[p3] = make_int2(v.w, __float_as_int(w.w));
}

// ---------------- conv1 gather: con nodes ----------------
__global__ __launch_bounds__(256) void k_gather_con(const int2* __restrict__ csr,
                                                    const unsigned int* __restrict__ start,
                                                    const unsigned int* __restrict__ deg,
                                                    const float* __restrict__ feat,
                                                    const float* __restrict__ W2,
                                                    const float* __restrict__ b2,
                                                    float* __restrict__ hs, int n) {
    __shared__ float sW[100], sb[10];
    for (int t = threadIdx.x; t < 100; t += blockDim.x) sW[t] = W2[t];
    if (threadIdx.x < 10) sb[threadIdx.x] = b2[threadIdx.x];
    __syncthreads();
    int i = blockIdx.x * blockDim.x + threadIdx.x;
    if (i >= n) return;
    unsigned int beg = start[i], cnt = deg[i], end = beg + cnt;
    float acc[HFE];
#pragma unroll
    for (int j = 0; j < HFE; j++) acc[j] = 0.0f;
    for (unsigned int p = beg; p < end; ++p) {
        int2 t = csr[p];
        float we = __int_as_float(t.y);
        const float2* row = (const float2*)(feat + (size_t)t.x * HFE);
#pragma unroll
        for (int j = 0; j < 5; j++) {
            float2 v = row[j];
            acc[2 * j]     = fmaf(we, v.x, acc[2 * j]);
            acc[2 * j + 1] = fmaf(we, v.y, acc[2 * j + 1]);
        }
    }
    float rs = rsqrtf(fmaxf((float)cnt, 1.0f));
#pragma unroll
    for (int j = 0; j < HFE; j++) acc[j] *= rs;
    float o[HFE];
#pragma unroll
    for (int k = 0; k < HFE; k++) {
        float t = sb[k];
#pragma unroll
        for (int j = 0; j < HFE; j++) t = fmaf(acc[j], sW[j * HFE + k], t);
        o[k] = fmaxf(t, 0.0f) * rs;   // relu, then prescale for conv2
    }
    float2* dst2 = (float2*)(hs + (size_t)i * HFE);
#pragma unroll
    for (int j = 0; j < 5; j++) dst2[j] = make_float2(o[2 * j], o[2 * j + 1]);
}

// ---------------- conv2 gather + dense + MLP + partial mean ----------------
__global__ __launch_bounds__(256) void k_gather_final(const int2* __restrict__ csr,
                                                      const unsigned int* __restrict__ start,
                                                      const unsigned int* __restrict__ deg,
                                                      const float* __restrict__ feat,
                                                      const float* __restrict__ W2,
                                                      const float* __restrict__ b2,
                                                      const float* __restrict__ Wo1,
                                                      const float* __restrict__ bo1,
                                                      const float* __restrict__ Wo2,
                                                      const float* __restrict__ bo2,
                                                      const float* __restrict__ Wo3,
                                                      const float* __restrict__ bo3,
                                                      double* __restrict__ partials, int n) {
    __shared__ float sW2[100], sb2[10], sWo1[100], sbo1[10], sWo2[100], sbo2[10], sWo3[10], sbo3;
    for (int t = threadIdx.x; t < 100; t += blockDim.x) {
        sW2[t] = W2[t]; sWo1[t] = Wo1[t]; sWo2[t] = Wo2[t];
    }
    if (threadIdx.x < 10) {
        sb2[threadIdx.x]  = b2[threadIdx.x];
        sbo1[threadIdx.x] = bo1[threadIdx.x];
        sbo2[threadIdx.x] = bo2[threadIdx.x];
        sWo3[threadIdx.x] = Wo3[threadIdx.x];
    }
    if (threadIdx.x == 0) sbo3 = bo3[0];
    __syncthreads();

    double accd = 0.0;
    int i = blockIdx.x * blockDim.x + threadIdx.x;
    if (i < n) {
        unsigned int beg = start[i], cnt = deg[i], end = beg + cnt;
        float acc[HFE];
#pragma unroll
        for (int j = 0; j < HFE; j++) acc[j] = 0.0f;
        for (unsigned int p = beg; p < end; ++p) {
            int2 t = csr[p];
            float we = __int_as_float(t.y);
            const float2* row = (const float2*)(feat + (size_t)t.x * HFE);
#pragma unroll
            for (int j = 0; j < 5; j++) {
                float2 v = row[j];
                acc[2 * j]     = fmaf(we, v.x, acc[2 * j]);
                acc[2 * j + 1] = fmaf(we, v.y, acc[2 * j + 1]);
            }
        }
        float rs = rsqrtf(fmaxf((float)cnt, 1.0f));
#pragma unroll
        for (int j = 0; j < HFE; j++) acc[j] *= rs;
        float h[HFE], z[HFE];
#pragma unroll
        for (int k = 0; k < HFE; k++) {
            float t = sb2[k];
#pragma unroll
            for (int j = 0; j < HFE; j++) t = fmaf(acc[j], sW2[j * HFE + k], t);
            h[k] = fmaxf(t, 0.0f);
        }
#pragma unroll
        for (int k = 0; k < HFE; k++) {
            float t = sbo1[k];
#pragma unroll
            for (int j = 0; j < HFE; j++) t = fmaf(h[j], sWo1[j * HFE + k], t);
            z[k] = fmaxf(t, 0.0f);
        }
        float t3 = sbo3;
#pragma unroll
        for (int k = 0; k < HFE; k++) {
            float t = sbo2[k];
#pragma unroll
            for (int j = 0; j < HFE; j++) t = fmaf(z[j], sWo2[j * HFE + k], t);
            t = fmaxf(t, 0.0f);
            t3 = fmaf(t, sWo3[k], t3);
        }
        accd = (double)t3;
    }

    __shared__ double red[256];
    red[threadIdx.x] = accd;
    __syncthreads();
    for (int off = blockDim.x / 2; off > 0; off >>= 1) {
        if (threadIdx.x < off) red[threadIdx.x] += red[threadIdx.x + off];
        __syncthreads();
    }
    if (threadIdx.x == 0) partials[blockIdx.x] = red[0];
}

__global__ __launch_bounds__(256) void k_out(const double* __restrict__ partials, int np,
                                             float* __restrict__ out) {
    __shared__ double red[256];
    double a = 0.0;
    for (int i = threadIdx.x; i < np; i += blockDim.x) a += partials[i];
    red[threadIdx.x] = a;
    __syncthreads();
    for (int off = 128; off > 0; off >>= 1) {
        if (threadIdx.x < off) red[threadIdx.x] += red[threadIdx.x + off];
        __syncthreads();
    }
    if (threadIdx.x == 0) out[0] = (float)(red[0] / (double)NVAR);
}

extern "C" void kernel_launch(void* const* d_in, const int* in_sizes, int n_in,
                              void* d_out, int out_size, void* d_ws, size_t ws_size,
                              hipStream_t stream) {
    const float* var_c  = (const float*)d_in[0];
    const float* var_x  = (const float*)d_in[1];
    const int*   e_src  = (const int*)d_in[3];
    const int*   e_dst  = (const int*)d_in[4];
    const float* e_w    = (const float*)d_in[5];
    const float* Wv     = (const float*)d_in[6];
    const float* bv     = (const float*)d_in[7];
    const float* W2     = (const float*)d_in[12];
    const float* b2     = (const float*)d_in[13];
    const float* Wo1    = (const float*)d_in[14];
    const float* bo1    = (const float*)d_in[15];
    const float* Wo2    = (const float*)d_in[16];
    const float* bo2    = (const float*)d_in[17];
    const float* Wo3    = (const float*)d_in[18];
    const float* bo3    = (const float*)d_in[19];
    float* out = (float*)d_out;
    const int ne = in_sizes[3];
    (void)n_in; (void)out_size; (void)ws_size;

    // ---- workspace layout (256B-aligned bump allocator) ----
    char* ws = (char*)d_ws;
    size_t off = 0;
    auto walloc = [&](size_t bytes) {
        void* p = ws + off;
        off = (off + bytes + 255) & ~(size_t)255;
        return p;
    };
    float*         Xs      = (float*)walloc((size_t)NVAR * HFE * 4);   // 40 MB
    int2*          csrC    = (int2*)walloc((size_t)ne * 8);            // 64 MB
    float*         hs_con  = (float*)walloc((size_t)NCON * HFE * 4);   // 20 MB
    ushort4*       rkS     = (ushort4*)walloc((size_t)ne * 2);         // 16 MB
    ushort4*       rkD     = (ushort4*)walloc((size_t)ne * 2);         // 16 MB
    unsigned int*  deg_var = (unsigned int*)walloc((size_t)NVAR * 4);  //  4 MB
    unsigned int*  deg_con = (unsigned int*)walloc((size_t)NCON * 4);  //  2 MB
    unsigned char* offV    = (unsigned char*)walloc((size_t)NVAR * NXCD); // 8 MB
    unsigned char* offC    = (unsigned char*)walloc((size_t)NCON * NXCD); // 4 MB
    unsigned int*  curV    = (unsigned int*)walloc((size_t)NVAR * 4);  //  4 MB
    unsigned int*  curC    = (unsigned int*)walloc((size_t)NCON * 4);  //  2 MB
    unsigned int*  bsumV   = (unsigned int*)walloc(4096);
    unsigned int*  bscanV  = (unsigned int*)walloc(4096);
    unsigned int*  bsumC   = (unsigned int*)walloc(4096);
    unsigned int*  bscanC  = (unsigned int*)walloc(4096);
    unsigned int*  bdummy  = (unsigned int*)walloc(256);
    double*        partials= (double*)walloc(3908 * 8);
    // Overlays (regions dead at use time):
    //   per-XCD histogram copies live inside csrC (48 MB of its 64 MB),
    //   dead before k_fill writes csrC.
    unsigned int*  dvc = (unsigned int*)csrC;                          // 32 MB
    unsigned int*  dcc = dvc + (size_t)NXCD * NVAR;                    // 16 MB
    //   csrV overlays Xs + csrC head (both dead after k_gather_con)
    int2*          csrV = (int2*)(ws + 0);                             // 64 MB

    const int B = 256;
    const int NBV = (NVAR + 1023) / 1024;   // 977
    const int NBC = (NCON + 1023) / 1024;   // 489
    const int NF  = (NVAR + B - 1) / B;     // 3907
    const int ne4 = ne / 4;

    // zero the per-XCD histogram copies (contiguous, 48 MB)
    hipMemsetAsync(dvc, 0, (size_t)NXCD * (NVAR + NCON) * 4, stream);

    // 1. degrees + local ranks (workgroup-scope atomics in XCD-local L2)
    k_degree_rank<<<(ne4 + B - 1) / B, B, 0, stream>>>(
        (const int4*)e_src, (const int4*)e_dst, rkS, rkD, dvc, dcc, ne4);

    // 2. reduce copies -> total degrees + per-XCD u8 base offsets
    k_xcdoff<<<(NVAR + B - 1) / B, B, 0, stream>>>(dvc, deg_var, offV, NVAR);
    k_xcdoff<<<(NCON + B - 1) / B, B, 0, stream>>>(dcc, deg_con, offC, NCON);

    // 3. exclusive scans -> segment starts
    k_scan_blocks<<<NBV, B, 0, stream>>>(deg_var, curV, bsumV, NVAR);
    k_scan_blocks<<<1,   B, 0, stream>>>(bsumV, bscanV, bdummy, NBV);
    k_scan_add   <<<NBV, B, 0, stream>>>(curV, bscanV, NVAR);
    k_scan_blocks<<<NBC, B, 0, stream>>>(deg_con, curC, bsumC, NCON);
    k_scan_blocks<<<1,   B, 0, stream>>>(bsumC, bscanC, bdummy, NBC);
    k_scan_add   <<<NBC, B, 0, stream>>>(curC, bscanC, NCON);

    // 4. var embedding (prescaled)
    k_xvar<<<(NVAR + B - 1) / B, B, 0, stream>>>(var_c, var_x, deg_var, Wv, bv, Xs, NVAR);

    // 5. conv1: atomic-free CSR fill by con, then gather
    k_fill<<<(ne4 + B - 1) / B, B, 0, stream>>>(
        (const int4*)e_dst, (const int4*)e_src, (const float4*)e_w, rkD, curC, offC, csrC, ne4);
    k_gather_con<<<(NCON + B - 1) / B, B, 0, stream>>>(csrC, curC, deg_con, Xs, W2, b2,
                                                       hs_con, NCON);

    // 6. conv2: atomic-free CSR fill by var (csrV overlays dead Xs/csrC-head)
    k_fill<<<(ne4 + B - 1) / B, B, 0, stream>>>(
        (const int4*)e_src, (const int4*)e_dst, (const float4*)e_w, rkS, curV, offV, csrV, ne4);
    k_gather_final<<<NF, B, 0, stream>>>(csrV, curV, deg_var, hs_con, W2, b2,
                                         Wo1, bo1, Wo2, bo2, Wo3, bo3, partials, NVAR);

    // 7. final mean
    k_out<<<1, B, 0, stream>>>(partials, NF, out);
}

// Round 5
// 1107.552 us; speedup vs baseline: 1.5748x; 1.5748x over previous
//
#include <hip/hip_runtime.h>

#define NVAR 1000000
#define NCON 500000
#define HFE 10
#define EPB 8192   // edges per pass-A block

// ============================================================================
// RADIX (atomic-free) path: 2-level counting sort builds CSR + degrees + starts
// ============================================================================

// ---- pass A0: per-block LDS histogram of high digits ----
__global__ __launch_bounds__(256) void kA_hist(const int* __restrict__ keys,
                                               unsigned int* __restrict__ bhist,
                                               int ne, int shift, int nblk) {
    __shared__ unsigned int h[1024];
    int tid = threadIdx.x, b = blockIdx.x;
    for (int t = tid; t < 1024; t += 256) h[t] = 0;
    __syncthreads();
    int beg = b * EPB, end = min(ne, beg + EPB);
    for (int e = beg + tid; e < end; e += 256) atomicAdd(&h[keys[e] >> shift], 1u);
    __syncthreads();
    for (int t = tid; t < 1024; t += 256) bhist[(size_t)t * nblk + b] = h[t];
}

// ---- pass A1: scatter edges into bucket-grouped order (LDS cursors only) ----
// payload int2: {x = w bits, y = (val << shift) | (key & mask)}
__global__ __launch_bounds__(256) void kA_scat(const int* __restrict__ keys,
                                               const int* __restrict__ vals,
                                               const float* __restrict__ w,
                                               const unsigned int* __restrict__ scanned,
                                               int2* __restrict__ bucketed,
                                               int ne, int shift, int nblk) {
    __shared__ unsigned int c[1024];
    int tid = threadIdx.x, b = blockIdx.x;
    for (int t = tid; t < 1024; t += 256) c[t] = scanned[(size_t)t * nblk + b];
    __syncthreads();
    int beg = b * EPB, end = min(ne, beg + EPB);
    unsigned mask = (1u << shift) - 1u;
    for (int e = beg + tid; e < end; e += 256) {
        int k = keys[e];
        unsigned pos = atomicAdd(&c[k >> shift], 1u);          // LDS atomic
        bucketed[pos] = make_int2(__float_as_int(w[e]),
                                  (vals[e] << shift) | (unsigned)(k & (int)mask));
    }
}

// ---- pass B: per-bucket LDS histogram -> deg/start + final CSR write ----
__global__ __launch_bounds__(256) void kB(const int2* __restrict__ bucketed,
                                          const unsigned int* __restrict__ scanned,
                                          unsigned int* __restrict__ deg,
                                          unsigned int* __restrict__ start,
                                          int2* __restrict__ csr,
                                          int nnodes, int shift, int nblk) {
    __shared__ unsigned int h[1024], s[1024], c[1024], sc[256];
    const int W = 1 << shift;
    const unsigned mask = (unsigned)(W - 1);
    int d = blockIdx.x, tid = threadIdx.x;
    unsigned base = scanned[(size_t)d * nblk];
    unsigned next = scanned[(size_t)(d + 1) * nblk];
    for (int t = tid; t < W; t += 256) h[t] = 0;
    __syncthreads();
    for (unsigned i = base + tid; i < next; i += 256)
        atomicAdd(&h[(unsigned)bucketed[i].y & mask], 1u);     // LDS atomic
    __syncthreads();
    // exclusive scan h[0..W) -> s (4 elems/thread + Hillis-Steele on 256 partials)
    unsigned v0 = 0, v1 = 0, v2 = 0, v3 = 0;
    int q = tid * 4;
    if (q < W) { v0 = h[q]; v1 = h[q + 1]; v2 = h[q + 2]; v3 = h[q + 3]; }
    sc[tid] = v0 + v1 + v2 + v3;
    __syncthreads();
    for (int dd = 1; dd < 256; dd <<= 1) {
        unsigned add = (tid >= dd) ? sc[tid - dd] : 0u;
        __syncthreads();
        sc[tid] += add;
        __syncthreads();
    }
    unsigned e = (tid == 0) ? 0u : sc[tid - 1];
    if (q < W) {
        s[q]     = e;
        s[q + 1] = e + v0;
        s[q + 2] = e + v0 + v1;
        s[q + 3] = e + v0 + v1 + v2;
    }
    __syncthreads();
    int lo = d << shift;
    for (int t = tid; t < W; t += 256) {
        int node = lo + t;
        if (node < nnodes) { deg[node] = h[t]; start[node] = base + s[t]; }
        c[t] = base + s[t];
    }
    __syncthreads();
    for (unsigned i = base + tid; i < next; i += 256) {
        int2 p = bucketed[i];
        unsigned pos = atomicAdd(&c[(unsigned)p.y & mask], 1u); // LDS atomic
        csr[pos] = make_int2(p.y >> shift, p.x);                // {neighbor, w bits}
    }
}

// ============================================================================
// FALLBACK path (round-3): global-atomic degree+rank, atomic-free fills
// ============================================================================

__global__ __launch_bounds__(256) void k_degree_rank(const int4* __restrict__ src4,
                                                     const int4* __restrict__ dst4,
                                                     uchar4* __restrict__ rkS,
                                                     uchar4* __restrict__ rkD,
                                                     unsigned int* __restrict__ deg_var,
                                                     unsigned int* __restrict__ deg_con,
                                                     int ne4) {
    int t = blockIdx.x * blockDim.x + threadIdx.x;
    if (t >= ne4) return;
    int4 s = src4[t];
    int4 d = dst4[t];
    unsigned int r0 = atomicAdd(&deg_var[s.x], 1u);
    unsigned int r1 = atomicAdd(&deg_var[s.y], 1u);
    unsigned int r2 = atomicAdd(&deg_var[s.z], 1u);
    unsigned int r3 = atomicAdd(&deg_var[s.w], 1u);
    unsigned int q0 = atomicAdd(&deg_con[d.x], 1u);
    unsigned int q1 = atomicAdd(&deg_con[d.y], 1u);
    unsigned int q2 = atomicAdd(&deg_con[d.z], 1u);
    unsigned int q3 = atomicAdd(&deg_con[d.w], 1u);
    rkS[t] = make_uchar4((unsigned char)r0, (unsigned char)r1, (unsigned char)r2, (unsigned char)r3);
    rkD[t] = make_uchar4((unsigned char)q0, (unsigned char)q1, (unsigned char)q2, (unsigned char)q3);
}

__global__ __launch_bounds__(256) void k_fill(const int4* __restrict__ key4,
                                              const int4* __restrict__ val4,
                                              const float4* __restrict__ w4,
                                              const uchar4* __restrict__ rk4,
                                              const unsigned int* __restrict__ cur,
                                              int2* __restrict__ csr, int ne4) {
    int t = blockIdx.x * blockDim.x + threadIdx.x;
    if (t >= ne4) return;
    int4 k = key4[t];
    int4 v = val4[t];
    float4 w = w4[t];
    uchar4 r = rk4[t];
    unsigned int p0 = cur[k.x] + r.x;
    unsigned int p1 = cur[k.y] + r.y;
    unsigned int p2 = cur[k.z] + r.z;
    unsigned int p3 = cur[k.w] + r.w;
    csr[p0] = make_int2(v.x, __float_as_int(w.x));
    csr[p1] = make_int2(v.y, __float_as_int(w.y));
    csr[p2] = make_int2(v.z, __float_as_int(w.z));
    csr[p3] = make_int2(v.w, __float_as_int(w.w));
}

// ============================================================================
// Shared kernels
// ============================================================================

__global__ __launch_bounds__(256) void k_scan_blocks(const unsigned int* __restrict__ in,
                                                     unsigned int* __restrict__ out,
                                                     unsigned int* __restrict__ bsum,
                                                     int n) {
    __shared__ unsigned int sT[256];
    int base = blockIdx.x * 1024 + threadIdx.x * 4;
    unsigned int v0 = 0, v1 = 0, v2 = 0, v3 = 0;
    if (base + 3 < n) {
        uint4 u = *(const uint4*)(in + base);
        v0 = u.x; v1 = u.y; v2 = u.z; v3 = u.w;
    } else {
        if (base     < n) v0 = in[base];
        if (base + 1 < n) v1 = in[base + 1];
        if (base + 2 < n) v2 = in[base + 2];
        if (base + 3 < n) v3 = in[base + 3];
    }
    sT[threadIdx.x] = v0 + v1 + v2 + v3;
    __syncthreads();
    for (int d = 1; d < 256; d <<= 1) {
        unsigned int add = (threadIdx.x >= (unsigned)d) ? sT[threadIdx.x - d] : 0u;
        __syncthreads();
        sT[threadIdx.x] += add;
        __syncthreads();
    }
    unsigned int excl = (threadIdx.x == 0) ? 0u : sT[threadIdx.x - 1];
    if (base     < n) out[base]     = excl;
    if (base + 1 < n) out[base + 1] = excl + v0;
    if (base + 2 < n) out[base + 2] = excl + v0 + v1;
    if (base + 3 < n) out[base + 3] = excl + v0 + v1 + v2;
    if (threadIdx.x == 255 && bsum) bsum[blockIdx.x] = sT[255];
}

__global__ __launch_bounds__(256) void k_scan_add(unsigned int* __restrict__ data,
                                                  const unsigned int* __restrict__ bscan,
                                                  int n) {
    int base = blockIdx.x * 1024 + threadIdx.x * 4;
    unsigned int add = bscan[blockIdx.x];
    if (base + 3 < n) {
        uint4 u = *(const uint4*)(data + base);
        u.x += add; u.y += add; u.z += add; u.w += add;
        *(uint4*)(data + base) = u;
    } else {
        if (base     < n) data[base]     += add;
        if (base + 1 < n) data[base + 1] += add;
        if (base + 2 < n) data[base + 2] += add;
        if (base + 3 < n) data[base + 3] += add;
    }
}

__global__ __launch_bounds__(256) void k_xvar(const float* __restrict__ var_c,
                                              const float* __restrict__ var_x,
                                              const unsigned int* __restrict__ deg_var,
                                              const float* __restrict__ Wv,
                                              const float* __restrict__ bv,
                                              float* __restrict__ Xs, int n) {
    int i = blockIdx.x * blockDim.x + threadIdx.x;
    if (i >= n) return;
    float c = var_c[i], x = var_x[i];
    float rs = rsqrtf(fmaxf((float)deg_var[i], 1.0f));
    float o[HFE];
#pragma unroll
    for (int j = 0; j < HFE; j++) {
        float t = fmaf(c, Wv[j], fmaf(x, Wv[HFE + j], bv[j]));
        o[j] = fmaxf(t, 0.0f) * rs;
    }
    float2* dst2 = (float2*)(Xs + (size_t)i * HFE);
#pragma unroll
    for (int j = 0; j < 5; j++) dst2[j] = make_float2(o[2 * j], o[2 * j + 1]);
}

__global__ __launch_bounds__(256) void k_gather_con(const int2* __restrict__ csr,
                                                    const unsigned int* __restrict__ start,
                                                    const unsigned int* __restrict__ deg,
                                                    const float* __restrict__ feat,
                                                    const float* __restrict__ W2,
                                                    const float* __restrict__ b2,
                                                    float* __restrict__ hs, int n) {
    __shared__ float sW[100], sb[10];
    for (int t = threadIdx.x; t < 100; t += blockDim.x) sW[t] = W2[t];
    if (threadIdx.x < 10) sb[threadIdx.x] = b2[threadIdx.x];
    __syncthreads();
    int i = blockIdx.x * blockDim.x + threadIdx.x;
    if (i >= n) return;
    unsigned int beg = start[i], cnt = deg[i], end = beg + cnt;
    float acc[HFE];
#pragma unroll
    for (int j = 0; j < HFE; j++) acc[j] = 0.0f;
    for (unsigned int p = beg; p < end; ++p) {
        int2 t = csr[p];
        float we = __int_as_float(t.y);
        const float2* row = (const float2*)(feat + (size_t)t.x * HFE);
#pragma unroll
        for (int j = 0; j < 5; j++) {
            float2 v = row[j];
            acc[2 * j]     = fmaf(we, v.x, acc[2 * j]);
            acc[2 * j + 1] = fmaf(we, v.y, acc[2 * j + 1]);
        }
    }
    float rs = rsqrtf(fmaxf((float)cnt, 1.0f));
#pragma unroll
    for (int j = 0; j < HFE; j++) acc[j] *= rs;
    float o[HFE];
#pragma unroll
    for (int k = 0; k < HFE; k++) {
        float t = sb[k];
#pragma unroll
        for (int j = 0; j < HFE; j++) t = fmaf(acc[j], sW[j * HFE + k], t);
        o[k] = fmaxf(t, 0.0f) * rs;   // relu, then prescale for conv2
    }
    float2* dst2 = (float2*)(hs + (size_t)i * HFE);
#pragma unroll
    for (int j = 0; j < 5; j++) dst2[j] = make_float2(o[2 * j], o[2 * j + 1]);
}

__global__ __launch_bounds__(256) void k_gather_final(const int2* __restrict__ csr,
                                                      const unsigned int* __restrict__ start,
                                                      const unsigned int* __restrict__ deg,
                                                      const float* __restrict__ feat,
                                                      const float* __restrict__ W2,
                                                      const float* __restrict__ b2,
                                                      const float* __restrict__ Wo1,
                                                      const float* __restrict__ bo1,
                                                      const float* __restrict__ Wo2,
                                                      const float* __restrict__ bo2,
                                                      const float* __restrict__ Wo3,
                                                      const float* __restrict__ bo3,
                                                      double* __restrict__ partials, int n) {
    __shared__ float sW2[100], sb2[10], sWo1[100], sbo1[10], sWo2[100], sbo2[10], sWo3[10], sbo3;
    for (int t = threadIdx.x; t < 100; t += blockDim.x) {
        sW2[t] = W2[t]; sWo1[t] = Wo1[t]; sWo2[t] = Wo2[t];
    }
    if (threadIdx.x < 10) {
        sb2[threadIdx.x]  = b2[threadIdx.x];
        sbo1[threadIdx.x] = bo1[threadIdx.x];
        sbo2[threadIdx.x] = bo2[threadIdx.x];
        sWo3[threadIdx.x] = Wo3[threadIdx.x];
    }
    if (threadIdx.x == 0) sbo3 = bo3[0];
    __syncthreads();

    double accd = 0.0;
    int i = blockIdx.x * blockDim.x + threadIdx.x;
    if (i < n) {
        unsigned int beg = start[i], cnt = deg[i], end = beg + cnt;
        float acc[HFE];
#pragma unroll
        for (int j = 0; j < HFE; j++) acc[j] = 0.0f;
        for (unsigned int p = beg; p < end; ++p) {
            int2 t = csr[p];
            float we = __int_as_float(t.y);
            const float2* row = (const float2*)(feat + (size_t)t.x * HFE);
#pragma unroll
            for (int j = 0; j < 5; j++) {
                float2 v = row[j];
                acc[2 * j]     = fmaf(we, v.x, acc[2 * j]);
                acc[2 * j + 1] = fmaf(we, v.y, acc[2 * j + 1]);
            }
        }
        float rs = rsqrtf(fmaxf((float)cnt, 1.0f));
#pragma unroll
        for (int j = 0; j < HFE; j++) acc[j] *= rs;
        float h[HFE], z[HFE];
#pragma unroll
        for (int k = 0; k < HFE; k++) {
            float t = sb2[k];
#pragma unroll
            for (int j = 0; j < HFE; j++) t = fmaf(acc[j], sW2[j * HFE + k], t);
            h[k] = fmaxf(t, 0.0f);
        }
#pragma unroll
        for (int k = 0; k < HFE; k++) {
            float t = sbo1[k];
#pragma unroll
            for (int j = 0; j < HFE; j++) t = fmaf(h[j], sWo1[j * HFE + k], t);
            z[k] = fmaxf(t, 0.0f);
        }
        float t3 = sbo3;
#pragma unroll
        for (int k = 0; k < HFE; k++) {
            float t = sbo2[k];
#pragma unroll
            for (int j = 0; j < HFE; j++) t = fmaf(z[j], sWo2[j * HFE + k], t);
            t = fmaxf(t, 0.0f);
            t3 = fmaf(t, sWo3[k], t3);
        }
        accd = (double)t3;
    }

    __shared__ double red[256];
    red[threadIdx.x] = accd;
    __syncthreads();
    for (int off = blockDim.x / 2; off > 0; off >>= 1) {
        if (threadIdx.x < off) red[threadIdx.x] += red[threadIdx.x + off];
        __syncthreads();
    }
    if (threadIdx.x == 0) partials[blockIdx.x] = red[0];
}

__global__ __launch_bounds__(256) void k_out(const double* __restrict__ partials, int np,
                                             float* __restrict__ out) {
    __shared__ double red[256];
    double a = 0.0;
    for (int i = threadIdx.x; i < np; i += blockDim.x) a += partials[i];
    red[threadIdx.x] = a;
    __syncthreads();
    for (int off = 128; off > 0; off >>= 1) {
        if (threadIdx.x < off) red[threadIdx.x] += red[threadIdx.x + off];
        __syncthreads();
    }
    if (threadIdx.x == 0) out[0] = (float)(red[0] / (double)NVAR);
}

// ============================================================================
// Launch
// ============================================================================

extern "C" void kernel_launch(void* const* d_in, const int* in_sizes, int n_in,
                              void* d_out, int out_size, void* d_ws, size_t ws_size,
                              hipStream_t stream) {
    const float* var_c  = (const float*)d_in[0];
    const float* var_x  = (const float*)d_in[1];
    const int*   e_src  = (const int*)d_in[3];
    const int*   e_dst  = (const int*)d_in[4];
    const float* e_w    = (const float*)d_in[5];
    const float* Wv     = (const float*)d_in[6];
    const float* bv     = (const float*)d_in[7];
    const float* W2     = (const float*)d_in[12];
    const float* b2     = (const float*)d_in[13];
    const float* Wo1    = (const float*)d_in[14];
    const float* bo1    = (const float*)d_in[15];
    const float* Wo2    = (const float*)d_in[16];
    const float* bo2    = (const float*)d_in[17];
    const float* Wo3    = (const float*)d_in[18];
    const float* bo3    = (const float*)d_in[19];
    float* out = (float*)d_out;
    const int ne = in_sizes[3];
    (void)n_in; (void)out_size;

    const int B = 256;
    const int NF = (NVAR + B - 1) / B;          // 3907 partials

    char* ws = (char*)d_ws;
    size_t off = 0;
    auto walloc = [&](size_t bytes) {
        void* p = ws + off;
        off = (off + bytes + 255) & ~(size_t)255;
        return p;
    };

    // ---- radix layout ----
    const int nblkA = (ne + EPB - 1) / EPB;     // 977
    const int scanN = 1024 * nblkA;             // 1,000,448
    const int NBs   = (scanN + 1023) / 1024;    // 978
    const int BKV   = (NVAR + 1023) >> 10;      // 977 buckets (shift 10)
    const int BKC   = (NCON + 511) >> 9;        // 977 buckets (shift 9)

    int2*          csrV     = (int2*)walloc((size_t)ne * 8);           // 64 MB
    int2*          csrC     = (int2*)walloc((size_t)ne * 8);           // 64 MB
    int2*          bucketed = (int2*)walloc((size_t)ne * 8);           // 64 MB (scratch)
    unsigned int*  bhist    = (unsigned int*)walloc((size_t)scanN * 4);//  4 MB
    unsigned int*  scanned  = (unsigned int*)walloc((size_t)scanN * 4);//  4 MB
    unsigned int*  deg_var  = (unsigned int*)walloc((size_t)NVAR * 4); //  4 MB
    unsigned int*  start_var= (unsigned int*)walloc((size_t)NVAR * 4); //  4 MB
    unsigned int*  deg_con  = (unsigned int*)walloc((size_t)NCON * 4); //  2 MB
    unsigned int*  start_con= (unsigned int*)walloc((size_t)NCON * 4); //  2 MB
    unsigned int*  bsum     = (unsigned int*)walloc(4096);
    unsigned int*  bscan    = (unsigned int*)walloc(4096);
    unsigned int*  bdummy   = (unsigned int*)walloc(256);
    double*        partials = (double*)walloc((size_t)NF * 8 + 64);
    size_t radix_need = off;
    // Xs + hs_con overlay the bucketed scratch (dead after both kB passes)
    float* Xs     = (float*)bucketed;                                  // 40 MB
    float* hs_con = (float*)((char*)bucketed + (size_t)NVAR * HFE * 4);// 20 MB

    if (ws_size >= radix_need) {
        // ---------------- atomic-free radix path ----------------
        // VAR direction: key = src (shift 10) -> csrV, deg_var, start_var
        kA_hist<<<nblkA, B, 0, stream>>>(e_src, bhist, ne, 10, nblkA);
        k_scan_blocks<<<NBs, B, 0, stream>>>(bhist, scanned, bsum, scanN);
        k_scan_blocks<<<1,   B, 0, stream>>>(bsum, bscan, bdummy, NBs);
        k_scan_add   <<<NBs, B, 0, stream>>>(scanned, bscan, scanN);
        kA_scat<<<nblkA, B, 0, stream>>>(e_src, e_dst, e_w, scanned, bucketed, ne, 10, nblkA);
        kB<<<BKV, B, 0, stream>>>(bucketed, scanned, deg_var, start_var, csrV, NVAR, 10, nblkA);

        // CON direction: key = dst (shift 9) -> csrC, deg_con, start_con
        kA_hist<<<nblkA, B, 0, stream>>>(e_dst, bhist, ne, 9, nblkA);
        k_scan_blocks<<<NBs, B, 0, stream>>>(bhist, scanned, bsum, scanN);
        k_scan_blocks<<<1,   B, 0, stream>>>(bsum, bscan, bdummy, NBs);
        k_scan_add   <<<NBs, B, 0, stream>>>(scanned, bscan, scanN);
        kA_scat<<<nblkA, B, 0, stream>>>(e_dst, e_src, e_w, scanned, bucketed, ne, 9, nblkA);
        kB<<<BKC, B, 0, stream>>>(bucketed, scanned, deg_con, start_con, csrC, NCON, 9, nblkA);

        // node pipeline (Xs/hs_con overlay bucketed, now dead)
        k_xvar<<<(NVAR + B - 1) / B, B, 0, stream>>>(var_c, var_x, deg_var, Wv, bv, Xs, NVAR);
        k_gather_con<<<(NCON + B - 1) / B, B, 0, stream>>>(csrC, start_con, deg_con, Xs,
                                                           W2, b2, hs_con, NCON);
        k_gather_final<<<NF, B, 0, stream>>>(csrV, start_var, deg_var, hs_con, W2, b2,
                                             Wo1, bo1, Wo2, bo2, Wo3, bo3, partials, NVAR);
        k_out<<<1, B, 0, stream>>>(partials, NF, out);
        return;
    }

    // ---------------- fallback: round-3 pipeline (152 MB) ----------------
    off = 0;
    float*         fXs      = (float*)walloc((size_t)NVAR * HFE * 4);
    int2*          fcsrC    = (int2*)walloc((size_t)ne * 8);
    float*         fhs_con  = (float*)walloc((size_t)NCON * HFE * 4);
    uchar4*        rkS      = (uchar4*)walloc((size_t)ne);
    uchar4*        rkD      = (uchar4*)walloc((size_t)ne);
    unsigned int*  fdeg_var = (unsigned int*)walloc((size_t)NVAR * 4);
    unsigned int*  fdeg_con = (unsigned int*)walloc((size_t)NCON * 4);
    unsigned int*  curV     = (unsigned int*)walloc((size_t)NVAR * 4);
    unsigned int*  curC     = (unsigned int*)walloc((size_t)NCON * 4);
    unsigned int*  bsumV    = (unsigned int*)walloc(4096);
    unsigned int*  bscanV   = (unsigned int*)walloc(4096);
    unsigned int*  bsumC    = (unsigned int*)walloc(4096);
    unsigned int*  bscanC   = (unsigned int*)walloc(4096);
    unsigned int*  fbdummy  = (unsigned int*)walloc(256);
    double*        fpart    = (double*)walloc((size_t)NF * 8 + 64);
    int2*          fcsrV    = (int2*)(ws + 0);   // overlays fXs + fcsrC head

    const int NBV = (NVAR + 1023) / 1024;
    const int NBC = (NCON + 1023) / 1024;
    const int ne4 = ne / 4;

    hipMemsetAsync(fdeg_var, 0, (size_t)NVAR * 4 + (size_t)NCON * 4, stream);
    k_degree_rank<<<(ne4 + B - 1) / B, B, 0, stream>>>(
        (const int4*)e_src, (const int4*)e_dst, rkS, rkD, fdeg_var, fdeg_con, ne4);
    k_scan_blocks<<<NBV, B, 0, stream>>>(fdeg_var, curV, bsumV, NVAR);
    k_scan_blocks<<<1,   B, 0, stream>>>(bsumV, bscanV, fbdummy, NBV);
    k_scan_add   <<<NBV, B, 0, stream>>>(curV, bscanV, NVAR);
    k_scan_blocks<<<NBC, B, 0, stream>>>(fdeg_con, curC, bsumC, NCON);
    k_scan_blocks<<<1,   B, 0, stream>>>(bsumC, bscanC, fbdummy, NBC);
    k_scan_add   <<<NBC, B, 0, stream>>>(curC, bscanC, NCON);
    k_xvar<<<(NVAR + B - 1) / B, B, 0, stream>>>(var_c, var_x, fdeg_var, Wv, bv, fXs, NVAR);
    k_fill<<<(ne4 + B - 1) / B, B, 0, stream>>>(
        (const int4*)e_dst, (const int4*)e_src, (const float4*)e_w, rkD, curC, fcsrC, ne4);
    k_gather_con<<<(NCON + B - 1) / B, B, 0, stream>>>(fcsrC, curC, fdeg_con, fXs, W2, b2,
                                                       fhs_con, NCON);
    k_fill<<<(ne4 + B - 1) / B, B, 0, stream>>>(
        (const int4*)e_src, (const int4*)e_dst, (const float4*)e_w, rkS, curV, fcsrV, ne4);
    k_gather_final<<<NF, B, 0, stream>>>(fcsrV, curV, fdeg_var, fhs_con, W2, b2,
                                         Wo1, bo1, Wo2, bo2, Wo3, bo3, fpart, NVAR);
    k_out<<<1, B, 0, stream>>>(fpart, NF, out);
}

// Round 6
// 1021.200 us; speedup vs baseline: 1.7079x; 1.0846x over previous
//
#include <hip/hip_runtime.h>

#define NVAR 1000000
#define NCON 500000
#define HFE 10
#define EPB 8192   // edges per pass-A block

// ============================================================================
// Radix (atomic-free) CSR build: shared by both paths
// ============================================================================

__global__ __launch_bounds__(256) void kA_hist(const int* __restrict__ keys,
                                               unsigned int* __restrict__ bhist,
                                               int ne, int shift, int nblk) {
    __shared__ unsigned int h[1024];
    int tid = threadIdx.x, b = blockIdx.x;
    for (int t = tid; t < 1024; t += 256) h[t] = 0;
    __syncthreads();
    int beg = b * EPB, end = min(ne, beg + EPB);
    for (int e = beg + tid; e < end; e += 256) atomicAdd(&h[keys[e] >> shift], 1u);
    __syncthreads();
    for (int t = tid; t < 1024; t += 256) bhist[(size_t)t * nblk + b] = h[t];
}

__global__ __launch_bounds__(256) void kA_scat(const int* __restrict__ keys,
                                               const int* __restrict__ vals,
                                               const float* __restrict__ w,
                                               const unsigned int* __restrict__ scanned,
                                               int2* __restrict__ bucketed,
                                               int ne, int shift, int nblk) {
    __shared__ unsigned int c[1024];
    int tid = threadIdx.x, b = blockIdx.x;
    for (int t = tid; t < 1024; t += 256) c[t] = scanned[(size_t)t * nblk + b];
    __syncthreads();
    int beg = b * EPB, end = min(ne, beg + EPB);
    unsigned mask = (1u << shift) - 1u;
    for (int e = beg + tid; e < end; e += 256) {
        int k = keys[e];
        unsigned pos = atomicAdd(&c[k >> shift], 1u);          // LDS atomic
        bucketed[pos] = make_int2(__float_as_int(w[e]),
                                  (vals[e] << shift) | (unsigned)(k & (int)mask));
    }
}

__global__ __launch_bounds__(256) void kB(const int2* __restrict__ bucketed,
                                          const unsigned int* __restrict__ scanned,
                                          unsigned int* __restrict__ deg,
                                          unsigned int* __restrict__ start,
                                          int2* __restrict__ csr,
                                          int nnodes, int shift, int nblk) {
    __shared__ unsigned int h[1024], s[1024], c[1024], sc[256];
    const int W = 1 << shift;
    const unsigned mask = (unsigned)(W - 1);
    int d = blockIdx.x, tid = threadIdx.x;
    unsigned base = scanned[(size_t)d * nblk];
    unsigned next = scanned[(size_t)(d + 1) * nblk];
    for (int t = tid; t < W; t += 256) h[t] = 0;
    __syncthreads();
    for (unsigned i = base + tid; i < next; i += 256)
        atomicAdd(&h[(unsigned)bucketed[i].y & mask], 1u);     // LDS atomic
    __syncthreads();
    unsigned v0 = 0, v1 = 0, v2 = 0, v3 = 0;
    int q = tid * 4;
    if (q < W) { v0 = h[q]; v1 = h[q + 1]; v2 = h[q + 2]; v3 = h[q + 3]; }
    sc[tid] = v0 + v1 + v2 + v3;
    __syncthreads();
    for (int dd = 1; dd < 256; dd <<= 1) {
        unsigned add = (tid >= dd) ? sc[tid - dd] : 0u;
        __syncthreads();
        sc[tid] += add;
        __syncthreads();
    }
    unsigned e = (tid == 0) ? 0u : sc[tid - 1];
    if (q < W) {
        s[q]     = e;
        s[q + 1] = e + v0;
        s[q + 2] = e + v0 + v1;
        s[q + 3] = e + v0 + v1 + v2;
    }
    __syncthreads();
    int lo = d << shift;
    for (int t = tid; t < W; t += 256) {
        int node = lo + t;
        if (node < nnodes) { deg[node] = h[t]; start[node] = base + s[t]; }
        c[t] = base + s[t];
    }
    __syncthreads();
    for (unsigned i = base + tid; i < next; i += 256) {
        int2 p = bucketed[i];
        unsigned pos = atomicAdd(&c[(unsigned)p.y & mask], 1u); // LDS atomic
        csr[pos] = make_int2(p.y >> shift, p.x);                // {neighbor, w bits}
    }
}

__global__ __launch_bounds__(256) void k_scan_blocks(const unsigned int* __restrict__ in,
                                                     unsigned int* __restrict__ out,
                                                     unsigned int* __restrict__ bsum,
                                                     int n) {
    __shared__ unsigned int sT[256];
    int base = blockIdx.x * 1024 + threadIdx.x * 4;
    unsigned int v0 = 0, v1 = 0, v2 = 0, v3 = 0;
    if (base + 3 < n) {
        uint4 u = *(const uint4*)(in + base);
        v0 = u.x; v1 = u.y; v2 = u.z; v3 = u.w;
    } else {
        if (base     < n) v0 = in[base];
        if (base + 1 < n) v1 = in[base + 1];
        if (base + 2 < n) v2 = in[base + 2];
        if (base + 3 < n) v3 = in[base + 3];
    }
    sT[threadIdx.x] = v0 + v1 + v2 + v3;
    __syncthreads();
    for (int d = 1; d < 256; d <<= 1) {
        unsigned int add = (threadIdx.x >= (unsigned)d) ? sT[threadIdx.x - d] : 0u;
        __syncthreads();
        sT[threadIdx.x] += add;
        __syncthreads();
    }
    unsigned int excl = (threadIdx.x == 0) ? 0u : sT[threadIdx.x - 1];
    if (base     < n) out[base]     = excl;
    if (base + 1 < n) out[base + 1] = excl + v0;
    if (base + 2 < n) out[base + 2] = excl + v0 + v1;
    if (base + 3 < n) out[base + 3] = excl + v0 + v1 + v2;
    if (threadIdx.x == 255 && bsum) bsum[blockIdx.x] = sT[255];
}

__global__ __launch_bounds__(256) void k_scan_add(unsigned int* __restrict__ data,
                                                  const unsigned int* __restrict__ bscan,
                                                  int n) {
    int base = blockIdx.x * 1024 + threadIdx.x * 4;
    unsigned int add = bscan[blockIdx.x];
    if (base + 3 < n) {
        uint4 u = *(const uint4*)(data + base);
        u.x += add; u.y += add; u.z += add; u.w += add;
        *(uint4*)(data + base) = u;
    } else {
        if (base     < n) data[base]     += add;
        if (base + 1 < n) data[base + 1] += add;
        if (base + 2 < n) data[base + 2] += add;
        if (base + 3 < n) data[base + 3] += add;
    }
}

__global__ __launch_bounds__(256) void k_out(const double* __restrict__ partials, int np,
                                             float* __restrict__ out) {
    __shared__ double red[256];
    double a = 0.0;
    for (int i = threadIdx.x; i < np; i += blockDim.x) a += partials[i];
    red[threadIdx.x] = a;
    __syncthreads();
    for (int off = 128; off > 0; off >>= 1) {
        if (threadIdx.x < off) red[threadIdx.x] += red[threadIdx.x + off];
        __syncthreads();
    }
    if (threadIdx.x == 0) out[0] = (float)(red[0] / (double)NVAR);
}

// ============================================================================
// PADDED path: 64 B feature rows, quad-per-node gathers
// ============================================================================

// var embedding -> [n][16] rows (10 used, rest zero), prescaled by rsqrt(deg)
__global__ __launch_bounds__(256) void k_xvar_p(const float* __restrict__ var_c,
                                                const float* __restrict__ var_x,
                                                const unsigned int* __restrict__ deg_var,
                                                const float* __restrict__ Wv,
                                                const float* __restrict__ bv,
                                                float* __restrict__ Xs, int n) {
    int i = blockIdx.x * blockDim.x + threadIdx.x;
    if (i >= n) return;
    float c = var_c[i], x = var_x[i];
    float rs = rsqrtf(fmaxf((float)deg_var[i], 1.0f));
    float o[16];
#pragma unroll
    for (int j = 0; j < HFE; j++) {
        float t = fmaf(c, Wv[j], fmaf(x, Wv[HFE + j], bv[j]));
        o[j] = fmaxf(t, 0.0f) * rs;
    }
#pragma unroll
    for (int j = HFE; j < 16; j++) o[j] = 0.0f;
    float4* dst4 = (float4*)(Xs + (size_t)i * 16);
#pragma unroll
    for (int j = 0; j < 4; j++)
        dst4[j] = make_float4(o[4 * j], o[4 * j + 1], o[4 * j + 2], o[4 * j + 3]);
}

// quad-per-node conv1: 4 lanes cooperatively load one 64 B row per edge
__global__ __launch_bounds__(256) void k_gq_con(const int2* __restrict__ csr,
                                                const unsigned int* __restrict__ start,
                                                const unsigned int* __restrict__ deg,
                                                const float* __restrict__ feat,  // [N][16]
                                                const float* __restrict__ W2,
                                                const float* __restrict__ b2,
                                                float* __restrict__ hs, int n) { // [n][16]
    __shared__ float sW[100], sb[10];
    for (int t = threadIdx.x; t < 100; t += blockDim.x) sW[t] = W2[t];
    if (threadIdx.x < 10) sb[threadIdx.x] = b2[threadIdx.x];
    __syncthreads();
    int t = blockIdx.x * blockDim.x + threadIdx.x;
    int quad = t >> 2, lane = t & 3;
    if (quad >= n) return;
    unsigned beg = start[quad], cnt = deg[quad], end = beg + cnt;
    float4 acc = make_float4(0.f, 0.f, 0.f, 0.f);
    for (unsigned p = beg; p < end; ++p) {
        int2 e = csr[p];                                  // quad-uniform (broadcast)
        float we = __int_as_float(e.y);
        float4 v = *(const float4*)(feat + (size_t)e.x * 16 + lane * 4);
        acc.x = fmaf(we, v.x, acc.x);
        acc.y = fmaf(we, v.y, acc.y);
        acc.z = fmaf(we, v.z, acc.z);
        acc.w = fmaf(we, v.w, acc.w);
    }
    float rs = rsqrtf(fmaxf((float)cnt, 1.0f));
    float a[10];
    a[0] = __shfl(acc.x, 0, 4); a[1] = __shfl(acc.y, 0, 4);
    a[2] = __shfl(acc.z, 0, 4); a[3] = __shfl(acc.w, 0, 4);
    a[4] = __shfl(acc.x, 1, 4); a[5] = __shfl(acc.y, 1, 4);
    a[6] = __shfl(acc.z, 1, 4); a[7] = __shfl(acc.w, 1, 4);
    a[8] = __shfl(acc.x, 2, 4); a[9] = __shfl(acc.y, 2, 4);
#pragma unroll
    for (int j = 0; j < 10; j++) a[j] *= rs;
    float o[12];
#pragma unroll
    for (int k = 0; k < 10; k++) {
        float s2 = sb[k];
#pragma unroll
        for (int j = 0; j < 10; j++) s2 = fmaf(a[j], sW[j * 10 + k], s2);
        o[k] = fmaxf(s2, 0.0f) * rs;   // relu + prescale for conv2
    }
    o[10] = 0.0f; o[11] = 0.0f;
    float4 wv = (lane < 3) ? make_float4(o[lane * 4], o[lane * 4 + 1],
                                         o[lane * 4 + 2], o[lane * 4 + 3])
                           : make_float4(0.f, 0.f, 0.f, 0.f);
    *(float4*)(hs + (size_t)quad * 16 + lane * 4) = wv;
}

// quad-per-node conv2 + MLP + partial mean
__global__ __launch_bounds__(256) void k_gq_final(const int2* __restrict__ csr,
                                                  const unsigned int* __restrict__ start,
                                                  const unsigned int* __restrict__ deg,
                                                  const float* __restrict__ feat, // [NCON][16]
                                                  const float* __restrict__ W2,
                                                  const float* __restrict__ b2,
                                                  const float* __restrict__ Wo1,
                                                  const float* __restrict__ bo1,
                                                  const float* __restrict__ Wo2,
                                                  const float* __restrict__ bo2,
                                                  const float* __restrict__ Wo3,
                                                  const float* __restrict__ bo3,
                                                  double* __restrict__ partials, int n) {
    __shared__ float sW2[100], sb2[10], sWo1[100], sbo1[10], sWo2[100], sbo2[10], sWo3[10], sbo3;
    for (int t = threadIdx.x; t < 100; t += blockDim.x) {
        sW2[t] = W2[t]; sWo1[t] = Wo1[t]; sWo2[t] = Wo2[t];
    }
    if (threadIdx.x < 10) {
        sb2[threadIdx.x]  = b2[threadIdx.x];
        sbo1[threadIdx.x] = bo1[threadIdx.x];
        sbo2[threadIdx.x] = bo2[threadIdx.x];
        sWo3[threadIdx.x] = Wo3[threadIdx.x];
    }
    if (threadIdx.x == 0) sbo3 = bo3[0];
    __syncthreads();

    int t = blockIdx.x * blockDim.x + threadIdx.x;
    int quad = t >> 2, lane = t & 3;
    double accd = 0.0;
    if (quad < n) {
        unsigned beg = start[quad], cnt = deg[quad], end = beg + cnt;
        float4 acc = make_float4(0.f, 0.f, 0.f, 0.f);
        for (unsigned p = beg; p < end; ++p) {
            int2 e = csr[p];
            float we = __int_as_float(e.y);
            float4 v = *(const float4*)(feat + (size_t)e.x * 16 + lane * 4);
            acc.x = fmaf(we, v.x, acc.x);
            acc.y = fmaf(we, v.y, acc.y);
            acc.z = fmaf(we, v.z, acc.z);
            acc.w = fmaf(we, v.w, acc.w);
        }
        float rs = rsqrtf(fmaxf((float)cnt, 1.0f));
        float a[10];
        a[0] = __shfl(acc.x, 0, 4); a[1] = __shfl(acc.y, 0, 4);
        a[2] = __shfl(acc.z, 0, 4); a[3] = __shfl(acc.w, 0, 4);
        a[4] = __shfl(acc.x, 1, 4); a[5] = __shfl(acc.y, 1, 4);
        a[6] = __shfl(acc.z, 1, 4); a[7] = __shfl(acc.w, 1, 4);
        a[8] = __shfl(acc.x, 2, 4); a[9] = __shfl(acc.y, 2, 4);
#pragma unroll
        for (int j = 0; j < 10; j++) a[j] *= rs;
        float h[10], z[10];
#pragma unroll
        for (int k = 0; k < 10; k++) {
            float s2 = sb2[k];
#pragma unroll
            for (int j = 0; j < 10; j++) s2 = fmaf(a[j], sW2[j * 10 + k], s2);
            h[k] = fmaxf(s2, 0.0f);
        }
#pragma unroll
        for (int k = 0; k < 10; k++) {
            float s2 = sbo1[k];
#pragma unroll
            for (int j = 0; j < 10; j++) s2 = fmaf(h[j], sWo1[j * 10 + k], s2);
            z[k] = fmaxf(s2, 0.0f);
        }
        float t3 = sbo3;
#pragma unroll
        for (int k = 0; k < 10; k++) {
            float s2 = sbo2[k];
#pragma unroll
            for (int j = 0; j < 10; j++) s2 = fmaf(z[j], sWo2[j * 10 + k], s2);
            s2 = fmaxf(s2, 0.0f);
            t3 = fmaf(s2, sWo3[k], t3);
        }
        if (lane == 0) accd = (double)t3;   // lanes 1-3 hold identical t3
    }

    __shared__ double red[256];
    red[threadIdx.x] = accd;
    __syncthreads();
    for (int off = blockDim.x / 2; off > 0; off >>= 1) {
        if (threadIdx.x < off) red[threadIdx.x] += red[threadIdx.x + off];
        __syncthreads();
    }
    if (threadIdx.x == 0) partials[blockIdx.x] = red[0];
}

// ============================================================================
// FALLBACK (round-5) node kernels: 40 B rows, thread-per-node
// ============================================================================

__global__ __launch_bounds__(256) void k_xvar(const float* __restrict__ var_c,
                                              const float* __restrict__ var_x,
                                              const unsigned int* __restrict__ deg_var,
                                              const float* __restrict__ Wv,
                                              const float* __restrict__ bv,
                                              float* __restrict__ Xs, int n) {
    int i = blockIdx.x * blockDim.x + threadIdx.x;
    if (i >= n) return;
    float c = var_c[i], x = var_x[i];
    float rs = rsqrtf(fmaxf((float)deg_var[i], 1.0f));
    float o[HFE];
#pragma unroll
    for (int j = 0; j < HFE; j++) {
        float t = fmaf(c, Wv[j], fmaf(x, Wv[HFE + j], bv[j]));
        o[j] = fmaxf(t, 0.0f) * rs;
    }
    float2* dst2 = (float2*)(Xs + (size_t)i * HFE);
#pragma unroll
    for (int j = 0; j < 5; j++) dst2[j] = make_float2(o[2 * j], o[2 * j + 1]);
}

__global__ __launch_bounds__(256) void k_gather_con(const int2* __restrict__ csr,
                                                    const unsigned int* __restrict__ start,
                                                    const unsigned int* __restrict__ deg,
                                                    const float* __restrict__ feat,
                                                    const float* __restrict__ W2,
                                                    const float* __restrict__ b2,
                                                    float* __restrict__ hs, int n) {
    __shared__ float sW[100], sb[10];
    for (int t = threadIdx.x; t < 100; t += blockDim.x) sW[t] = W2[t];
    if (threadIdx.x < 10) sb[threadIdx.x] = b2[threadIdx.x];
    __syncthreads();
    int i = blockIdx.x * blockDim.x + threadIdx.x;
    if (i >= n) return;
    unsigned int beg = start[i], cnt = deg[i], end = beg + cnt;
    float acc[HFE];
#pragma unroll
    for (int j = 0; j < HFE; j++) acc[j] = 0.0f;
    for (unsigned int p = beg; p < end; ++p) {
        int2 t = csr[p];
        float we = __int_as_float(t.y);
        const float2* row = (const float2*)(feat + (size_t)t.x * HFE);
#pragma unroll
        for (int j = 0; j < 5; j++) {
            float2 v = row[j];
            acc[2 * j]     = fmaf(we, v.x, acc[2 * j]);
            acc[2 * j + 1] = fmaf(we, v.y, acc[2 * j + 1]);
        }
    }
    float rs = rsqrtf(fmaxf((float)cnt, 1.0f));
#pragma unroll
    for (int j = 0; j < HFE; j++) acc[j] *= rs;
    float o[HFE];
#pragma unroll
    for (int k = 0; k < HFE; k++) {
        float t = sb[k];
#pragma unroll
        for (int j = 0; j < HFE; j++) t = fmaf(acc[j], sW[j * HFE + k], t);
        o[k] = fmaxf(t, 0.0f) * rs;
    }
    float2* dst2 = (float2*)(hs + (size_t)i * HFE);
#pragma unroll
    for (int j = 0; j < 5; j++) dst2[j] = make_float2(o[2 * j], o[2 * j + 1]);
}

__global__ __launch_bounds__(256) void k_gather_final(const int2* __restrict__ csr,
                                                      const unsigned int* __restrict__ start,
                                                      const unsigned int* __restrict__ deg,
                                                      const float* __restrict__ feat,
                                                      const float* __restrict__ W2,
                                                      const float* __restrict__ b2,
                                                      const float* __restrict__ Wo1,
                                                      const float* __restrict__ bo1,
                                                      const float* __restrict__ Wo2,
                                                      const float* __restrict__ bo2,
                                                      const float* __restrict__ Wo3,
                                                      const float* __restrict__ bo3,
                                                      double* __restrict__ partials, int n) {
    __shared__ float sW2[100], sb2[10], sWo1[100], sbo1[10], sWo2[100], sbo2[10], sWo3[10], sbo3;
    for (int t = threadIdx.x; t < 100; t += blockDim.x) {
        sW2[t] = W2[t]; sWo1[t] = Wo1[t]; sWo2[t] = Wo2[t];
    }
    if (threadIdx.x < 10) {
        sb2[threadIdx.x]  = b2[threadIdx.x];
        sbo1[threadIdx.x] = bo1[threadIdx.x];
        sbo2[threadIdx.x] = bo2[threadIdx.x];
        sWo3[threadIdx.x] = Wo3[threadIdx.x];
    }
    if (threadIdx.x == 0) sbo3 = bo3[0];
    __syncthreads();

    double accd = 0.0;
    int i = blockIdx.x * blockDim.x + threadIdx.x;
    if (i < n) {
        unsigned int beg = start[i], cnt = deg[i], end = beg + cnt;
        float acc[HFE];
#pragma unroll
        for (int j = 0; j < HFE; j++) acc[j] = 0.0f;
        for (unsigned int p = beg; p < end; ++p) {
            int2 t = csr[p];
            float we = __int_as_float(t.y);
            const float2* row = (const float2*)(feat + (size_t)t.x * HFE);
#pragma unroll
            for (int j = 0; j < 5; j++) {
                float2 v = row[j];
                acc[2 * j]     = fmaf(we, v.x, acc[2 * j]);
                acc[2 * j + 1] = fmaf(we, v.y, acc[2 * j + 1]);
            }
        }
        float rs = rsqrtf(fmaxf((float)cnt, 1.0f));
#pragma unroll
        for (int j = 0; j < HFE; j++) acc[j] *= rs;
        float h[HFE], z[HFE];
#pragma unroll
        for (int k = 0; k < HFE; k++) {
            float t = sb2[k];
#pragma unroll
            for (int j = 0; j < HFE; j++) t = fmaf(acc[j], sW2[j * HFE + k], t);
            h[k] = fmaxf(t, 0.0f);
        }
#pragma unroll
        for (int k = 0; k < HFE; k++) {
            float t = sbo1[k];
#pragma unroll
            for (int j = 0; j < HFE; j++) t = fmaf(h[j], sWo1[j * HFE + k], t);
            z[k] = fmaxf(t, 0.0f);
        }
        float t3 = sbo3;
#pragma unroll
        for (int k = 0; k < HFE; k++) {
            float t = sbo2[k];
#pragma unroll
            for (int j = 0; j < HFE; j++) t = fmaf(z[j], sWo2[j * HFE + k], t);
            t = fmaxf(t, 0.0f);
            t3 = fmaf(t, sWo3[k], t3);
        }
        accd = (double)t3;
    }

    __shared__ double red[256];
    red[threadIdx.x] = accd;
    __syncthreads();
    for (int off = blockDim.x / 2; off > 0; off >>= 1) {
        if (threadIdx.x < off) red[threadIdx.x] += red[threadIdx.x + off];
        __syncthreads();
    }
    if (threadIdx.x == 0) partials[blockIdx.x] = red[0];
}

// ============================================================================
// Launch
// ============================================================================

extern "C" void kernel_launch(void* const* d_in, const int* in_sizes, int n_in,
                              void* d_out, int out_size, void* d_ws, size_t ws_size,
                              hipStream_t stream) {
    const float* var_c  = (const float*)d_in[0];
    const float* var_x  = (const float*)d_in[1];
    const int*   e_src  = (const int*)d_in[3];
    const int*   e_dst  = (const int*)d_in[4];
    const float* e_w    = (const float*)d_in[5];
    const float* Wv     = (const float*)d_in[6];
    const float* bv     = (const float*)d_in[7];
    const float* W2     = (const float*)d_in[12];
    const float* b2     = (const float*)d_in[13];
    const float* Wo1    = (const float*)d_in[14];
    const float* bo1    = (const float*)d_in[15];
    const float* Wo2    = (const float*)d_in[16];
    const float* bo2    = (const float*)d_in[17];
    const float* Wo3    = (const float*)d_in[18];
    const float* bo3    = (const float*)d_in[19];
    float* out = (float*)d_out;
    const int ne = in_sizes[3];
    (void)n_in; (void)out_size;

    const int B = 256;
    const int nblkA = (ne + EPB - 1) / EPB;     // 977
    const int scanN = 1024 * nblkA;
    const int NBs   = (scanN + 1023) / 1024;
    const int BKV   = (NVAR + 1023) >> 10;      // shift 10
    const int BKC   = (NCON + 511) >> 9;        // shift 9

    char* ws = (char*)d_ws;
    size_t off = 0;
    auto walloc = [&](size_t bytes) {
        void* p = ws + off;
        off = (off + bytes + 255) & ~(size_t)255;
        return p;
    };

    // ---- padded-path layout ----
    const int NFQ = (4 * NVAR + B - 1) / B;     // 15625 partials (quad final)
    int2*          csrV     = (int2*)walloc((size_t)ne * 8);             // 64 MB
    int2*          csrC     = (int2*)walloc((size_t)ne * 8);             // 64 MB
    int2*          bucketed = (int2*)walloc((size_t)ne * 8);             // 64 MB
    unsigned int*  bhist    = (unsigned int*)walloc((size_t)scanN * 4);  //  4 MB
    unsigned int*  scanned  = (unsigned int*)walloc((size_t)scanN * 4);  //  4 MB
    unsigned int*  deg_var  = (unsigned int*)walloc((size_t)NVAR * 4);
    unsigned int*  start_var= (unsigned int*)walloc((size_t)NVAR * 4);
    unsigned int*  deg_con  = (unsigned int*)walloc((size_t)NCON * 4);
    unsigned int*  start_con= (unsigned int*)walloc((size_t)NCON * 4);
    unsigned int*  bsum     = (unsigned int*)walloc(4096);
    unsigned int*  bscan    = (unsigned int*)walloc(4096);
    unsigned int*  bdummy   = (unsigned int*)walloc(256);
    double*        partials = (double*)walloc((size_t)NFQ * 8 + 64);
    float*         hs64     = (float*)walloc((size_t)NCON * 16 * 4);     // 32 MB
    size_t need_padded = off;
    float* Xs64 = (float*)bucketed;    // 64 MB overlay: bucketed dead after sortC

    if (ws_size >= need_padded) {
        // ---- sort V (key = src, shift 10) ----
        kA_hist<<<nblkA, B, 0, stream>>>(e_src, bhist, ne, 10, nblkA);
        k_scan_blocks<<<NBs, B, 0, stream>>>(bhist, scanned, bsum, scanN);
        k_scan_blocks<<<1,   B, 0, stream>>>(bsum, bscan, bdummy, NBs);
        k_scan_add   <<<NBs, B, 0, stream>>>(scanned, bscan, scanN);
        kA_scat<<<nblkA, B, 0, stream>>>(e_src, e_dst, e_w, scanned, bucketed, ne, 10, nblkA);
        kB<<<BKV, B, 0, stream>>>(bucketed, scanned, deg_var, start_var, csrV, NVAR, 10, nblkA);
        // ---- sort C (key = dst, shift 9) ----
        kA_hist<<<nblkA, B, 0, stream>>>(e_dst, bhist, ne, 9, nblkA);
        k_scan_blocks<<<NBs, B, 0, stream>>>(bhist, scanned, bsum, scanN);
        k_scan_blocks<<<1,   B, 0, stream>>>(bsum, bscan, bdummy, NBs);
        k_scan_add   <<<NBs, B, 0, stream>>>(scanned, bscan, scanN);
        kA_scat<<<nblkA, B, 0, stream>>>(e_dst, e_src, e_w, scanned, bucketed, ne, 9, nblkA);
        kB<<<BKC, B, 0, stream>>>(bucketed, scanned, deg_con, start_con, csrC, NCON, 9, nblkA);
        // ---- node pipeline (padded rows, quad gathers) ----
        k_xvar_p<<<(NVAR + B - 1) / B, B, 0, stream>>>(var_c, var_x, deg_var, Wv, bv,
                                                       Xs64, NVAR);
        k_gq_con<<<(4 * NCON + B - 1) / B, B, 0, stream>>>(csrC, start_con, deg_con, Xs64,
                                                           W2, b2, hs64, NCON);
        k_gq_final<<<NFQ, B, 0, stream>>>(csrV, start_var, deg_var, hs64, W2, b2,
                                          Wo1, bo1, Wo2, bo2, Wo3, bo3, partials, NVAR);
        k_out<<<1, B, 0, stream>>>(partials, NFQ, out);
        return;
    }

    // ---- fallback: round-5 layout (unpadded, thread-per-node gathers) ----
    off = 0;
    const int NF = (NVAR + B - 1) / B;
    int2*          fcsrV     = (int2*)walloc((size_t)ne * 8);
    int2*          fcsrC     = (int2*)walloc((size_t)ne * 8);
    int2*          fbuck     = (int2*)walloc((size_t)ne * 8);
    unsigned int*  fbhist    = (unsigned int*)walloc((size_t)scanN * 4);
    unsigned int*  fscanned  = (unsigned int*)walloc((size_t)scanN * 4);
    unsigned int*  fdeg_var  = (unsigned int*)walloc((size_t)NVAR * 4);
    unsigned int*  fstart_var= (unsigned int*)walloc((size_t)NVAR * 4);
    unsigned int*  fdeg_con  = (unsigned int*)walloc((size_t)NCON * 4);
    unsigned int*  fstart_con= (unsigned int*)walloc((size_t)NCON * 4);
    unsigned int*  fbsum     = (unsigned int*)walloc(4096);
    unsigned int*  fbscan    = (unsigned int*)walloc(4096);
    unsigned int*  fbdummy   = (unsigned int*)walloc(256);
    double*        fpart     = (double*)walloc((size_t)NF * 8 + 64);
    float* fXs     = (float*)fbuck;                                   // 40 MB overlay
    float* fhs_con = (float*)((char*)fbuck + (size_t)NVAR * HFE * 4); // 20 MB overlay

    kA_hist<<<nblkA, B, 0, stream>>>(e_src, fbhist, ne, 10, nblkA);
    k_scan_blocks<<<NBs, B, 0, stream>>>(fbhist, fscanned, fbsum, scanN);
    k_scan_blocks<<<1,   B, 0, stream>>>(fbsum, fbscan, fbdummy, NBs);
    k_scan_add   <<<NBs, B, 0, stream>>>(fscanned, fbscan, scanN);
    kA_scat<<<nblkA, B, 0, stream>>>(e_src, e_dst, e_w, fscanned, fbuck, ne, 10, nblkA);
    kB<<<BKV, B, 0, stream>>>(fbuck, fscanned, fdeg_var, fstart_var, fcsrV, NVAR, 10, nblkA);
    kA_hist<<<nblkA, B, 0, stream>>>(e_dst, fbhist, ne, 9, nblkA);
    k_scan_blocks<<<NBs, B, 0, stream>>>(fbhist, fscanned, fbsum, scanN);
    k_scan_blocks<<<1,   B, 0, stream>>>(fbsum, fbscan, fbdummy, NBs);
    k_scan_add   <<<NBs, B, 0, stream>>>(fscanned, fbscan, scanN);
    kA_scat<<<nblkA, B, 0, stream>>>(e_dst, e_src, e_w, fscanned, fbuck, ne, 9, nblkA);
    kB<<<BKC, B, 0, stream>>>(fbuck, fscanned, fdeg_con, fstart_con, fcsrC, NCON, 9, nblkA);
    k_xvar<<<(NVAR + B - 1) / B, B, 0, stream>>>(var_c, var_x, fdeg_var, Wv, bv, fXs, NVAR);
    k_gather_con<<<(NCON + B - 1) / B, B, 0, stream>>>(fcsrC, fstart_con, fdeg_con, fXs,
                                                       W2, b2, fhs_con, NCON);
    k_gather_final<<<NF, B, 0, stream>>>(fcsrV, fstart_var, fdeg_var, fhs_con, W2, b2,
                                         Wo1, bo1, Wo2, bo2, Wo3, bo3, fpart, NVAR);
    k_out<<<1, B, 0, stream>>>(fpart, NF, out);
}

// Round 7
// 966.098 us; speedup vs baseline: 1.8053x; 1.0570x over previous
//
#include <hip/hip_runtime.h>

#define NVAR 1000000
#define NCON 500000
#define HFE 10
#define EPB 8192   // edges per pass-A block

// ============================================================================
// Radix (atomic-free) CSR build: shared by both paths
// ============================================================================

__global__ __launch_bounds__(256) void kA_hist(const int* __restrict__ keys,
                                               unsigned int* __restrict__ bhist,
                                               int ne, int shift, int nblk) {
    __shared__ unsigned int h[1024];
    int tid = threadIdx.x, b = blockIdx.x;
    for (int t = tid; t < 1024; t += 256) h[t] = 0;
    __syncthreads();
    int beg = b * EPB, end = min(ne, beg + EPB);
    for (int e = beg + tid; e < end; e += 256) atomicAdd(&h[keys[e] >> shift], 1u);
    __syncthreads();
    for (int t = tid; t < 1024; t += 256) bhist[(size_t)t * nblk + b] = h[t];
}

__global__ __launch_bounds__(256) void kA_scat(const int* __restrict__ keys,
                                               const int* __restrict__ vals,
                                               const float* __restrict__ w,
                                               const unsigned int* __restrict__ scanned,
                                               int2* __restrict__ bucketed,
                                               int ne, int shift, int nblk) {
    __shared__ unsigned int c[1024];
    int tid = threadIdx.x, b = blockIdx.x;
    for (int t = tid; t < 1024; t += 256) c[t] = scanned[(size_t)t * nblk + b];
    __syncthreads();
    int beg = b * EPB, end = min(ne, beg + EPB);
    unsigned mask = (1u << shift) - 1u;
    for (int e = beg + tid; e < end; e += 256) {
        int k = keys[e];
        unsigned pos = atomicAdd(&c[k >> shift], 1u);          // LDS atomic
        bucketed[pos] = make_int2(__float_as_int(w[e]),
                                  (vals[e] << shift) | (unsigned)(k & (int)mask));
    }
}

__global__ __launch_bounds__(256) void kB(const int2* __restrict__ bucketed,
                                          const unsigned int* __restrict__ scanned,
                                          unsigned int* __restrict__ deg,
                                          unsigned int* __restrict__ start,
                                          int2* __restrict__ csr,
                                          int nnodes, int shift, int nblk) {
    __shared__ unsigned int h[1024], s[1024], c[1024], sc[256];
    const int W = 1 << shift;
    const unsigned mask = (unsigned)(W - 1);
    int d = blockIdx.x, tid = threadIdx.x;
    unsigned base = scanned[(size_t)d * nblk];
    unsigned next = scanned[(size_t)(d + 1) * nblk];
    for (int t = tid; t < W; t += 256) h[t] = 0;
    __syncthreads();
    for (unsigned i = base + tid; i < next; i += 256)
        atomicAdd(&h[(unsigned)bucketed[i].y & mask], 1u);     // LDS atomic
    __syncthreads();
    unsigned v0 = 0, v1 = 0, v2 = 0, v3 = 0;
    int q = tid * 4;
    if (q < W) { v0 = h[q]; v1 = h[q + 1]; v2 = h[q + 2]; v3 = h[q + 3]; }
    sc[tid] = v0 + v1 + v2 + v3;
    __syncthreads();
    for (int dd = 1; dd < 256; dd <<= 1) {
        unsigned add = (tid >= dd) ? sc[tid - dd] : 0u;
        __syncthreads();
        sc[tid] += add;
        __syncthreads();
    }
    unsigned e = (tid == 0) ? 0u : sc[tid - 1];
    if (q < W) {
        s[q]     = e;
        s[q + 1] = e + v0;
        s[q + 2] = e + v0 + v1;
        s[q + 3] = e + v0 + v1 + v2;
    }
    __syncthreads();
    int lo = d << shift;
    for (int t = tid; t < W; t += 256) {
        int node = lo + t;
        if (node < nnodes) { deg[node] = h[t]; start[node] = base + s[t]; }
        c[t] = base + s[t];
    }
    __syncthreads();
    for (unsigned i = base + tid; i < next; i += 256) {
        int2 p = bucketed[i];
        unsigned pos = atomicAdd(&c[(unsigned)p.y & mask], 1u); // LDS atomic
        csr[pos] = make_int2(p.y >> shift, p.x);                // {neighbor, w bits}
    }
}

__global__ __launch_bounds__(256) void k_scan_blocks(const unsigned int* __restrict__ in,
                                                     unsigned int* __restrict__ out,
                                                     unsigned int* __restrict__ bsum,
                                                     int n) {
    __shared__ unsigned int sT[256];
    int base = blockIdx.x * 1024 + threadIdx.x * 4;
    unsigned int v0 = 0, v1 = 0, v2 = 0, v3 = 0;
    if (base + 3 < n) {
        uint4 u = *(const uint4*)(in + base);
        v0 = u.x; v1 = u.y; v2 = u.z; v3 = u.w;
    } else {
        if (base     < n) v0 = in[base];
        if (base + 1 < n) v1 = in[base + 1];
        if (base + 2 < n) v2 = in[base + 2];
        if (base + 3 < n) v3 = in[base + 3];
    }
    sT[threadIdx.x] = v0 + v1 + v2 + v3;
    __syncthreads();
    for (int d = 1; d < 256; d <<= 1) {
        unsigned int add = (threadIdx.x >= (unsigned)d) ? sT[threadIdx.x - d] : 0u;
        __syncthreads();
        sT[threadIdx.x] += add;
        __syncthreads();
    }
    unsigned int excl = (threadIdx.x == 0) ? 0u : sT[threadIdx.x - 1];
    if (base     < n) out[base]     = excl;
    if (base + 1 < n) out[base + 1] = excl + v0;
    if (base + 2 < n) out[base + 2] = excl + v0 + v1;
    if (base + 3 < n) out[base + 3] = excl + v0 + v1 + v2;
    if (threadIdx.x == 255 && bsum) bsum[blockIdx.x] = sT[255];
}

__global__ __launch_bounds__(256) void k_scan_add(unsigned int* __restrict__ data,
                                                  const unsigned int* __restrict__ bscan,
                                                  int n) {
    int base = blockIdx.x * 1024 + threadIdx.x * 4;
    unsigned int add = bscan[blockIdx.x];
    if (base + 3 < n) {
        uint4 u = *(const uint4*)(data + base);
        u.x += add; u.y += add; u.z += add; u.w += add;
        *(uint4*)(data + base) = u;
    } else {
        if (base     < n) data[base]     += add;
        if (base + 1 < n) data[base + 1] += add;
        if (base + 2 < n) data[base + 2] += add;
        if (base + 3 < n) data[base + 3] += add;
    }
}

__global__ __launch_bounds__(256) void k_out(const double* __restrict__ partials, int np,
                                             float* __restrict__ out) {
    __shared__ double red[256];
    double a = 0.0;
    for (int i = threadIdx.x; i < np; i += blockDim.x) a += partials[i];
    red[threadIdx.x] = a;
    __syncthreads();
    for (int off = 128; off > 0; off >>= 1) {
        if (threadIdx.x < off) red[threadIdx.x] += red[threadIdx.x + off];
        __syncthreads();
    }
    if (threadIdx.x == 0) out[0] = (float)(red[0] / (double)NVAR);
}

// ============================================================================
// PADDED path: 64 B feature rows, quad-per-node gathers, 4-edge unroll
// ============================================================================

__global__ __launch_bounds__(256) void k_xvar_p(const float* __restrict__ var_c,
                                                const float* __restrict__ var_x,
                                                const unsigned int* __restrict__ deg_var,
                                                const float* __restrict__ Wv,
                                                const float* __restrict__ bv,
                                                float* __restrict__ Xs, int n) {
    int i = blockIdx.x * blockDim.x + threadIdx.x;
    if (i >= n) return;
    float c = var_c[i], x = var_x[i];
    float rs = rsqrtf(fmaxf((float)deg_var[i], 1.0f));
    float o[16];
#pragma unroll
    for (int j = 0; j < HFE; j++) {
        float t = fmaf(c, Wv[j], fmaf(x, Wv[HFE + j], bv[j]));
        o[j] = fmaxf(t, 0.0f) * rs;
    }
#pragma unroll
    for (int j = HFE; j < 16; j++) o[j] = 0.0f;
    float4* dst4 = (float4*)(Xs + (size_t)i * 16);
#pragma unroll
    for (int j = 0; j < 4; j++)
        dst4[j] = make_float4(o[4 * j], o[4 * j + 1], o[4 * j + 2], o[4 * j + 3]);
}

// quad-per-node conv1 with 4-edge unroll (4 independent gathers in flight)
__global__ __launch_bounds__(256) void k_gq_con(const int2* __restrict__ csr,
                                                const unsigned int* __restrict__ start,
                                                const unsigned int* __restrict__ deg,
                                                const float* __restrict__ feat,  // [N][16]
                                                const float* __restrict__ W2,
                                                const float* __restrict__ b2,
                                                float* __restrict__ hs, int n) { // [n][16]
    __shared__ float sW[100], sb[10];
    for (int t = threadIdx.x; t < 100; t += blockDim.x) sW[t] = W2[t];
    if (threadIdx.x < 10) sb[threadIdx.x] = b2[threadIdx.x];
    __syncthreads();
    int t = blockIdx.x * blockDim.x + threadIdx.x;
    int quad = t >> 2, lane = t & 3;
    if (quad >= n) return;
    unsigned beg = start[quad], cnt = deg[quad], end = beg + cnt;
    float4 acc = make_float4(0.f, 0.f, 0.f, 0.f);
    unsigned p = beg;
    for (; p + 4 <= end; p += 4) {
        int2 e0 = csr[p];
        int2 e1 = csr[p + 1];
        int2 e2 = csr[p + 2];
        int2 e3 = csr[p + 3];
        float4 v0 = *(const float4*)(feat + (size_t)e0.x * 16 + lane * 4);
        float4 v1 = *(const float4*)(feat + (size_t)e1.x * 16 + lane * 4);
        float4 v2 = *(const float4*)(feat + (size_t)e2.x * 16 + lane * 4);
        float4 v3 = *(const float4*)(feat + (size_t)e3.x * 16 + lane * 4);
        float w0 = __int_as_float(e0.y), w1 = __int_as_float(e1.y);
        float w2 = __int_as_float(e2.y), w3 = __int_as_float(e3.y);
        acc.x = fmaf(w0, v0.x, acc.x); acc.y = fmaf(w0, v0.y, acc.y);
        acc.z = fmaf(w0, v0.z, acc.z); acc.w = fmaf(w0, v0.w, acc.w);
        acc.x = fmaf(w1, v1.x, acc.x); acc.y = fmaf(w1, v1.y, acc.y);
        acc.z = fmaf(w1, v1.z, acc.z); acc.w = fmaf(w1, v1.w, acc.w);
        acc.x = fmaf(w2, v2.x, acc.x); acc.y = fmaf(w2, v2.y, acc.y);
        acc.z = fmaf(w2, v2.z, acc.z); acc.w = fmaf(w2, v2.w, acc.w);
        acc.x = fmaf(w3, v3.x, acc.x); acc.y = fmaf(w3, v3.y, acc.y);
        acc.z = fmaf(w3, v3.z, acc.z); acc.w = fmaf(w3, v3.w, acc.w);
    }
    for (; p < end; ++p) {
        int2 e = csr[p];
        float we = __int_as_float(e.y);
        float4 v = *(const float4*)(feat + (size_t)e.x * 16 + lane * 4);
        acc.x = fmaf(we, v.x, acc.x);
        acc.y = fmaf(we, v.y, acc.y);
        acc.z = fmaf(we, v.z, acc.z);
        acc.w = fmaf(we, v.w, acc.w);
    }
    float rs = rsqrtf(fmaxf((float)cnt, 1.0f));
    float a[10];
    a[0] = __shfl(acc.x, 0, 4); a[1] = __shfl(acc.y, 0, 4);
    a[2] = __shfl(acc.z, 0, 4); a[3] = __shfl(acc.w, 0, 4);
    a[4] = __shfl(acc.x, 1, 4); a[5] = __shfl(acc.y, 1, 4);
    a[6] = __shfl(acc.z, 1, 4); a[7] = __shfl(acc.w, 1, 4);
    a[8] = __shfl(acc.x, 2, 4); a[9] = __shfl(acc.y, 2, 4);
#pragma unroll
    for (int j = 0; j < 10; j++) a[j] *= rs;
    float o[12];
#pragma unroll
    for (int k = 0; k < 10; k++) {
        float s2 = sb[k];
#pragma unroll
        for (int j = 0; j < 10; j++) s2 = fmaf(a[j], sW[j * 10 + k], s2);
        o[k] = fmaxf(s2, 0.0f) * rs;   // relu + prescale for conv2
    }
    o[10] = 0.0f; o[11] = 0.0f;
    float4 wv = (lane < 3) ? make_float4(o[lane * 4], o[lane * 4 + 1],
                                         o[lane * 4 + 2], o[lane * 4 + 3])
                           : make_float4(0.f, 0.f, 0.f, 0.f);
    *(float4*)(hs + (size_t)quad * 16 + lane * 4) = wv;
}

// quad-per-node conv2 + MLP + partial mean, 4-edge unroll
__global__ __launch_bounds__(256) void k_gq_final(const int2* __restrict__ csr,
                                                  const unsigned int* __restrict__ start,
                                                  const unsigned int* __restrict__ deg,
                                                  const float* __restrict__ feat, // [NCON][16]
                                                  const float* __restrict__ W2,
                                                  const float* __restrict__ b2,
                                                  const float* __restrict__ Wo1,
                                                  const float* __restrict__ bo1,
                                                  const float* __restrict__ Wo2,
                                                  const float* __restrict__ bo2,
                                                  const float* __restrict__ Wo3,
                                                  const float* __restrict__ bo3,
                                                  double* __restrict__ partials, int n) {
    __shared__ float sW2[100], sb2[10], sWo1[100], sbo1[10], sWo2[100], sbo2[10], sWo3[10], sbo3;
    for (int t = threadIdx.x; t < 100; t += blockDim.x) {
        sW2[t] = W2[t]; sWo1[t] = Wo1[t]; sWo2[t] = Wo2[t];
    }
    if (threadIdx.x < 10) {
        sb2[threadIdx.x]  = b2[threadIdx.x];
        sbo1[threadIdx.x] = bo1[threadIdx.x];
        sbo2[threadIdx.x] = bo2[threadIdx.x];
        sWo3[threadIdx.x] = Wo3[threadIdx.x];
    }
    if (threadIdx.x == 0) sbo3 = bo3[0];
    __syncthreads();

    int t = blockIdx.x * blockDim.x + threadIdx.x;
    int quad = t >> 2, lane = t & 3;
    double accd = 0.0;
    if (quad < n) {
        unsigned beg = start[quad], cnt = deg[quad], end = beg + cnt;
        float4 acc = make_float4(0.f, 0.f, 0.f, 0.f);
        unsigned p = beg;
        for (; p + 4 <= end; p += 4) {
            int2 e0 = csr[p];
            int2 e1 = csr[p + 1];
            int2 e2 = csr[p + 2];
            int2 e3 = csr[p + 3];
            float4 v0 = *(const float4*)(feat + (size_t)e0.x * 16 + lane * 4);
            float4 v1 = *(const float4*)(feat + (size_t)e1.x * 16 + lane * 4);
            float4 v2 = *(const float4*)(feat + (size_t)e2.x * 16 + lane * 4);
            float4 v3 = *(const float4*)(feat + (size_t)e3.x * 16 + lane * 4);
            float w0 = __int_as_float(e0.y), w1 = __int_as_float(e1.y);
            float w2 = __int_as_float(e2.y), w3 = __int_as_float(e3.y);
            acc.x = fmaf(w0, v0.x, acc.x); acc.y = fmaf(w0, v0.y, acc.y);
            acc.z = fmaf(w0, v0.z, acc.z); acc.w = fmaf(w0, v0.w, acc.w);
            acc.x = fmaf(w1, v1.x, acc.x); acc.y = fmaf(w1, v1.y, acc.y);
            acc.z = fmaf(w1, v1.z, acc.z); acc.w = fmaf(w1, v1.w, acc.w);
            acc.x = fmaf(w2, v2.x, acc.x); acc.y = fmaf(w2, v2.y, acc.y);
            acc.z = fmaf(w2, v2.z, acc.z); acc.w = fmaf(w2, v2.w, acc.w);
            acc.x = fmaf(w3, v3.x, acc.x); acc.y = fmaf(w3, v3.y, acc.y);
            acc.z = fmaf(w3, v3.z, acc.z); acc.w = fmaf(w3, v3.w, acc.w);
        }
        for (; p < end; ++p) {
            int2 e = csr[p];
            float we = __int_as_float(e.y);
            float4 v = *(const float4*)(feat + (size_t)e.x * 16 + lane * 4);
            acc.x = fmaf(we, v.x, acc.x);
            acc.y = fmaf(we, v.y, acc.y);
            acc.z = fmaf(we, v.z, acc.z);
            acc.w = fmaf(we, v.w, acc.w);
        }
        float rs = rsqrtf(fmaxf((float)cnt, 1.0f));
        float a[10];
        a[0] = __shfl(acc.x, 0, 4); a[1] = __shfl(acc.y, 0, 4);
        a[2] = __shfl(acc.z, 0, 4); a[3] = __shfl(acc.w, 0, 4);
        a[4] = __shfl(acc.x, 1, 4); a[5] = __shfl(acc.y, 1, 4);
        a[6] = __shfl(acc.z, 1, 4); a[7] = __shfl(acc.w, 1, 4);
        a[8] = __shfl(acc.x, 2, 4); a[9] = __shfl(acc.y, 2, 4);
#pragma unroll
        for (int j = 0; j < 10; j++) a[j] *= rs;
        float h[10], z[10];
#pragma unroll
        for (int k = 0; k < 10; k++) {
            float s2 = sb2[k];
#pragma unroll
            for (int j = 0; j < 10; j++) s2 = fmaf(a[j], sW2[j * 10 + k], s2);
            h[k] = fmaxf(s2, 0.0f);
        }
#pragma unroll
        for (int k = 0; k < 10; k++) {
            float s2 = sbo1[k];
#pragma unroll
            for (int j = 0; j < 10; j++) s2 = fmaf(h[j], sWo1[j * 10 + k], s2);
            z[k] = fmaxf(s2, 0.0f);
        }
        float t3 = sbo3;
#pragma unroll
        for (int k = 0; k < 10; k++) {
            float s2 = sbo2[k];
#pragma unroll
            for (int j = 0; j < 10; j++) s2 = fmaf(z[j], sWo2[j * 10 + k], s2);
            s2 = fmaxf(s2, 0.0f);
            t3 = fmaf(s2, sWo3[k], t3);
        }
        if (lane == 0) accd = (double)t3;   // lanes 1-3 hold identical t3
    }

    __shared__ double red[256];
    red[threadIdx.x] = accd;
    __syncthreads();
    for (int off = blockDim.x / 2; off > 0; off >>= 1) {
        if (threadIdx.x < off) red[threadIdx.x] += red[threadIdx.x + off];
        __syncthreads();
    }
    if (threadIdx.x == 0) partials[blockIdx.x] = red[0];
}

// ============================================================================
// FALLBACK (round-5) node kernels: 40 B rows, thread-per-node
// ============================================================================

__global__ __launch_bounds__(256) void k_xvar(const float* __restrict__ var_c,
                                              const float* __restrict__ var_x,
                                              const unsigned int* __restrict__ deg_var,
                                              const float* __restrict__ Wv,
                                              const float* __restrict__ bv,
                                              float* __restrict__ Xs, int n) {
    int i = blockIdx.x * blockDim.x + threadIdx.x;
    if (i >= n) return;
    float c = var_c[i], x = var_x[i];
    float rs = rsqrtf(fmaxf((float)deg_var[i], 1.0f));
    float o[HFE];
#pragma unroll
    for (int j = 0; j < HFE; j++) {
        float t = fmaf(c, Wv[j], fmaf(x, Wv[HFE + j], bv[j]));
        o[j] = fmaxf(t, 0.0f) * rs;
    }
    float2* dst2 = (float2*)(Xs + (size_t)i * HFE);
#pragma unroll
    for (int j = 0; j < 5; j++) dst2[j] = make_float2(o[2 * j], o[2 * j + 1]);
}

__global__ __launch_bounds__(256) void k_gather_con(const int2* __restrict__ csr,
                                                    const unsigned int* __restrict__ start,
                                                    const unsigned int* __restrict__ deg,
                                                    const float* __restrict__ feat,
                                                    const float* __restrict__ W2,
                                                    const float* __restrict__ b2,
                                                    float* __restrict__ hs, int n) {
    __shared__ float sW[100], sb[10];
    for (int t = threadIdx.x; t < 100; t += blockDim.x) sW[t] = W2[t];
    if (threadIdx.x < 10) sb[threadIdx.x] = b2[threadIdx.x];
    __syncthreads();
    int i = blockIdx.x * blockDim.x + threadIdx.x;
    if (i >= n) return;
    unsigned int beg = start[i], cnt = deg[i], end = beg + cnt;
    float acc[HFE];
#pragma unroll
    for (int j = 0; j < HFE; j++) acc[j] = 0.0f;
    for (unsigned int p = beg; p < end; ++p) {
        int2 t = csr[p];
        float we = __int_as_float(t.y);
        const float2* row = (const float2*)(feat + (size_t)t.x * HFE);
#pragma unroll
        for (int j = 0; j < 5; j++) {
            float2 v = row[j];
            acc[2 * j]     = fmaf(we, v.x, acc[2 * j]);
            acc[2 * j + 1] = fmaf(we, v.y, acc[2 * j + 1]);
        }
    }
    float rs = rsqrtf(fmaxf((float)cnt, 1.0f));
#pragma unroll
    for (int j = 0; j < HFE; j++) acc[j] *= rs;
    float o[HFE];
#pragma unroll
    for (int k = 0; k < HFE; k++) {
        float t = sb[k];
#pragma unroll
        for (int j = 0; j < HFE; j++) t = fmaf(acc[j], sW[j * HFE + k], t);
        o[k] = fmaxf(t, 0.0f) * rs;
    }
    float2* dst2 = (float2*)(hs + (size_t)i * HFE);
#pragma unroll
    for (int j = 0; j < 5; j++) dst2[j] = make_float2(o[2 * j], o[2 * j + 1]);
}

__global__ __launch_bounds__(256) void k_gather_final(const int2* __restrict__ csr,
                                                      const unsigned int* __restrict__ start,
                                                      const unsigned int* __restrict__ deg,
                                                      const float* __restrict__ feat,
                                                      const float* __restrict__ W2,
                                                      const float* __restrict__ b2,
                                                      const float* __restrict__ Wo1,
                                                      const float* __restrict__ bo1,
                                                      const float* __restrict__ Wo2,
                                                      const float* __restrict__ bo2,
                                                      const float* __restrict__ Wo3,
                                                      const float* __restrict__ bo3,
                                                      double* __restrict__ partials, int n) {
    __shared__ float sW2[100], sb2[10], sWo1[100], sbo1[10], sWo2[100], sbo2[10], sWo3[10], sbo3;
    for (int t = threadIdx.x; t < 100; t += blockDim.x) {
        sW2[t] = W2[t]; sWo1[t] = Wo1[t]; sWo2[t] = Wo2[t];
    }
    if (threadIdx.x < 10) {
        sb2[threadIdx.x]  = b2[threadIdx.x];
        sbo1[threadIdx.x] = bo1[threadIdx.x];
        sbo2[threadIdx.x] = bo2[threadIdx.x];
        sWo3[threadIdx.x] = Wo3[threadIdx.x];
    }
    if (threadIdx.x == 0) sbo3 = bo3[0];
    __syncthreads();

    double accd = 0.0;
    int i = blockIdx.x * blockDim.x + threadIdx.x;
    if (i < n) {
        unsigned int beg = start[i], cnt = deg[i], end = beg + cnt;
        float acc[HFE];
#pragma unroll
        for (int j = 0; j < HFE; j++) acc[j] = 0.0f;
        for (unsigned int p = beg; p < end; ++p) {
            int2 t = csr[p];
            float we = __int_as_float(t.y);
            const float2* row = (const float2*)(feat + (size_t)t.x * HFE);
#pragma unroll
            for (int j = 0; j < 5; j++) {
                float2 v = row[j];
                acc[2 * j]     = fmaf(we, v.x, acc[2 * j]);
                acc[2 * j + 1] = fmaf(we, v.y, acc[2 * j + 1]);
            }
        }
        float rs = rsqrtf(fmaxf((float)cnt, 1.0f));
#pragma unroll
        for (int j = 0; j < HFE; j++) acc[j] *= rs;
        float h[HFE], z[HFE];
#pragma unroll
        for (int k = 0; k < HFE; k++) {
            float t = sb2[k];
#pragma unroll
            for (int j = 0; j < HFE; j++) t = fmaf(acc[j], sW2[j * HFE + k], t);
            h[k] = fmaxf(t, 0.0f);
        }
#pragma unroll
        for (int k = 0; k < HFE; k++) {
            float t = sbo1[k];
#pragma unroll
            for (int j = 0; j < HFE; j++) t = fmaf(h[j], sWo1[j * HFE + k], t);
            z[k] = fmaxf(t, 0.0f);
        }
        float t3 = sbo3;
#pragma unroll
        for (int k = 0; k < HFE; k++) {
            float t = sbo2[k];
#pragma unroll
            for (int j = 0; j < HFE; j++) t = fmaf(z[j], sWo2[j * HFE + k], t);
            t = fmaxf(t, 0.0f);
            t3 = fmaf(t, sWo3[k], t3);
        }
        accd = (double)t3;
    }

    __shared__ double red[256];
    red[threadIdx.x] = accd;
    __syncthreads();
    for (int off = blockDim.x / 2; off > 0; off >>= 1) {
        if (threadIdx.x < off) red[threadIdx.x] += red[threadIdx.x + off];
        __syncthreads();
    }
    if (threadIdx.x == 0) partials[blockIdx.x] = red[0];
}

// ============================================================================
// Launch
// ============================================================================

extern "C" void kernel_launch(void* const* d_in, const int* in_sizes, int n_in,
                              void* d_out, int out_size, void* d_ws, size_t ws_size,
                              hipStream_t stream) {
    const float* var_c  = (const float*)d_in[0];
    const float* var_x  = (const float*)d_in[1];
    const int*   e_src  = (const int*)d_in[3];
    const int*   e_dst  = (const int*)d_in[4];
    const float* e_w    = (const float*)d_in[5];
    const float* Wv     = (const float*)d_in[6];
    const float* bv     = (const float*)d_in[7];
    const float* W2     = (const float*)d_in[12];
    const float* b2     = (const float*)d_in[13];
    const float* Wo1    = (const float*)d_in[14];
    const float* bo1    = (const float*)d_in[15];
    const float* Wo2    = (const float*)d_in[16];
    const float* bo2    = (const float*)d_in[17];
    const float* Wo3    = (const float*)d_in[18];
    const float* bo3    = (const float*)d_in[19];
    float* out = (float*)d_out;
    const int ne = in_sizes[3];
    (void)n_in; (void)out_size;

    const int B = 256;
    const int nblkA = (ne + EPB - 1) / EPB;     // 977
    const int scanN = 1024 * nblkA;
    const int NBs   = (scanN + 1023) / 1024;
    const int BKV   = (NVAR + 1023) >> 10;      // shift 10
    const int BKC   = (NCON + 511) >> 9;        // shift 9

    char* ws = (char*)d_ws;
    size_t off = 0;
    auto walloc = [&](size_t bytes) {
        void* p = ws + off;
        off = (off + bytes + 255) & ~(size_t)255;
        return p;
    };

    // ---- padded-path layout ----
    const int NFQ = (4 * NVAR + B - 1) / B;     // 15625 partials (quad final)
    int2*          csrV     = (int2*)walloc((size_t)ne * 8);             // 64 MB
    int2*          csrC     = (int2*)walloc((size_t)ne * 8);             // 64 MB
    int2*          bucketed = (int2*)walloc((size_t)ne * 8);             // 64 MB
    unsigned int*  bhist    = (unsigned int*)walloc((size_t)scanN * 4);  //  4 MB
    unsigned int*  scanned  = (unsigned int*)walloc((size_t)scanN * 4);  //  4 MB
    unsigned int*  deg_var  = (unsigned int*)walloc((size_t)NVAR * 4);
    unsigned int*  start_var= (unsigned int*)walloc((size_t)NVAR * 4);
    unsigned int*  deg_con  = (unsigned int*)walloc((size_t)NCON * 4);
    unsigned int*  start_con= (unsigned int*)walloc((size_t)NCON * 4);
    unsigned int*  bsum     = (unsigned int*)walloc(4096);
    unsigned int*  bscan    = (unsigned int*)walloc(4096);
    unsigned int*  bdummy   = (unsigned int*)walloc(256);
    double*        partials = (double*)walloc((size_t)NFQ * 8 + 64);
    float*         hs64     = (float*)walloc((size_t)NCON * 16 * 4);     // 32 MB
    size_t need_padded = off;
    float* Xs64 = (float*)bucketed;    // 64 MB overlay: bucketed dead after sortC

    if (ws_size >= need_padded) {
        // ---- sort V (key = src, shift 10) ----
        kA_hist<<<nblkA, B, 0, stream>>>(e_src, bhist, ne, 10, nblkA);
        k_scan_blocks<<<NBs, B, 0, stream>>>(bhist, scanned, bsum, scanN);
        k_scan_blocks<<<1,   B, 0, stream>>>(bsum, bscan, bdummy, NBs);
        k_scan_add   <<<NBs, B, 0, stream>>>(scanned, bscan, scanN);
        kA_scat<<<nblkA, B, 0, stream>>>(e_src, e_dst, e_w, scanned, bucketed, ne, 10, nblkA);
        kB<<<BKV, B, 0, stream>>>(bucketed, scanned, deg_var, start_var, csrV, NVAR, 10, nblkA);
        // ---- sort C (key = dst, shift 9) ----
        kA_hist<<<nblkA, B, 0, stream>>>(e_dst, bhist, ne, 9, nblkA);
        k_scan_blocks<<<NBs, B, 0, stream>>>(bhist, scanned, bsum, scanN);
        k_scan_blocks<<<1,   B, 0, stream>>>(bsum, bscan, bdummy, NBs);
        k_scan_add   <<<NBs, B, 0, stream>>>(scanned, bscan, scanN);
        kA_scat<<<nblkA, B, 0, stream>>>(e_dst, e_src, e_w, scanned, bucketed, ne, 9, nblkA);
        kB<<<BKC, B, 0, stream>>>(bucketed, scanned, deg_con, start_con, csrC, NCON, 9, nblkA);
        // ---- node pipeline (padded rows, quad gathers, unrolled) ----
        k_xvar_p<<<(NVAR + B - 1) / B, B, 0, stream>>>(var_c, var_x, deg_var, Wv, bv,
                                                       Xs64, NVAR);
        k_gq_con<<<(4 * NCON + B - 1) / B, B, 0, stream>>>(csrC, start_con, deg_con, Xs64,
                                                           W2, b2, hs64, NCON);
        k_gq_final<<<NFQ, B, 0, stream>>>(csrV, start_var, deg_var, hs64, W2, b2,
                                          Wo1, bo1, Wo2, bo2, Wo3, bo3, partials, NVAR);
        k_out<<<1, B, 0, stream>>>(partials, NFQ, out);
        return;
    }

    // ---- fallback: round-5 layout (unpadded, thread-per-node gathers) ----
    off = 0;
    const int NF = (NVAR + B - 1) / B;
    int2*          fcsrV     = (int2*)walloc((size_t)ne * 8);
    int2*          fcsrC     = (int2*)walloc((size_t)ne * 8);
    int2*          fbuck     = (int2*)walloc((size_t)ne * 8);
    unsigned int*  fbhist    = (unsigned int*)walloc((size_t)scanN * 4);
    unsigned int*  fscanned  = (unsigned int*)walloc((size_t)scanN * 4);
    unsigned int*  fdeg_var  = (unsigned int*)walloc((size_t)NVAR * 4);
    unsigned int*  fstart_var= (unsigned int*)walloc((size_t)NVAR * 4);
    unsigned int*  fdeg_con  = (unsigned int*)walloc((size_t)NCON * 4);
    unsigned int*  fstart_con= (unsigned int*)walloc((size_t)NCON * 4);
    unsigned int*  fbsum     = (unsigned int*)walloc(4096);
    unsigned int*  fbscan    = (unsigned int*)walloc(4096);
    unsigned int*  fbdummy   = (unsigned int*)walloc(256);
    double*        fpart     = (double*)walloc((size_t)NF * 8 + 64);
    float* fXs     = (float*)fbuck;                                   // 40 MB overlay
    float* fhs_con = (float*)((char*)fbuck + (size_t)NVAR * HFE * 4); // 20 MB overlay

    kA_hist<<<nblkA, B, 0, stream>>>(e_src, fbhist, ne, 10, nblkA);
    k_scan_blocks<<<NBs, B, 0, stream>>>(fbhist, fscanned, fbsum, scanN);
    k_scan_blocks<<<1,   B, 0, stream>>>(fbsum, fbscan, fbdummy, NBs);
    k_scan_add   <<<NBs, B, 0, stream>>>(fscanned, fbscan, scanN);
    kA_scat<<<nblkA, B, 0, stream>>>(e_src, e_dst, e_w, fscanned, fbuck, ne, 10, nblkA);
    kB<<<BKV, B, 0, stream>>>(fbuck, fscanned, fdeg_var, fstart_var, fcsrV, NVAR, 10, nblkA);
    kA_hist<<<nblkA, B, 0, stream>>>(e_dst, fbhist, ne, 9, nblkA);
    k_scan_blocks<<<NBs, B, 0, stream>>>(fbhist, fscanned, fbsum, scanN);
    k_scan_blocks<<<1,   B, 0, stream>>>(fbsum, fbscan, fbdummy, NBs);
    k_scan_add   <<<NBs, B, 0, stream>>>(fscanned, fbscan, scanN);
    kA_scat<<<nblkA, B, 0, stream>>>(e_dst, e_src, e_w, fscanned, fbuck, ne, 9, nblkA);
    kB<<<BKC, B, 0, stream>>>(fbuck, fscanned, fdeg_con, fstart_con, fcsrC, NCON, 9, nblkA);
    k_xvar<<<(NVAR + B - 1) / B, B, 0, stream>>>(var_c, var_x, fdeg_var, Wv, bv, fXs, NVAR);
    k_gather_con<<<(NCON + B - 1) / B, B, 0, stream>>>(fcsrC, fstart_con, fdeg_con, fXs,
                                                       W2, b2, fhs_con, NCON);
    k_gather_final<<<NF, B, 0, stream>>>(fcsrV, fstart_var, fdeg_var, fhs_con, W2, b2,
                                         Wo1, bo1, Wo2, bo2, Wo3, bo3, fpart, NVAR);
    k_out<<<1, B, 0, stream>>>(fpart, NF, out);
}